// Round 10
// baseline (266.852 us; speedup 1.0000x reference)
//
#include <hip/hip_runtime.h>
#include <hip/hip_bf16.h>
#include <math.h>

#define B_ 64
#define P_ 128
#define C_ 72
#define PADC 80    // f16 global row stride for A/Bc
#define BCS 88     // LDS row stride in halfs (176B -> 2-way banks, free)
#define IT 4       // i-rows per edge block (1 per wave)

typedef __attribute__((ext_vector_type(8))) _Float16 half8v;
typedef __attribute__((ext_vector_type(4))) _Float16 half4v;
typedef __attribute__((ext_vector_type(4))) float f32x4;
typedef __attribute__((ext_vector_type(2))) float f32x2;
typedef __attribute__((ext_vector_type(4))) unsigned int u32x4;

// precomputed weight-fragment table (units: half8v, 64 per fragment)
#define FRAG_WE2  0          // We2 kt=0,1 (K32) [+unused kt2], 15 frags
#define FRAG_WE1A (15 * 64)  // We1 rows 0..71, 15 frags
#define FRAG_WE1B (30 * 64)  // We1 rows 72..143 (+be1 @k=72), 15 frags
#define FRAG_WH1  (45 * 64)  // Wh1 (+bh1 @k=144), 25 frags
#define FRAG_WH2  (70 * 64)  // Wh2 (+bh2 @k=72), 15 frags
#define NFRAG 85             // + 5 K16-tail frags (half4v) appended

__device__ __forceinline__ float psi_f(float v) {
    float a = fabsf(v);
    return copysignf(__logf(1.0f + a), v);
}
template <int CTRL>
__device__ __forceinline__ float dpp_add(float v) {
    int s = __builtin_amdgcn_update_dpp(0, __builtin_bit_cast(int, v), CTRL, 0xF, 0xF, true);
    return v + __builtin_bit_cast(float, s);
}
// full sum across each 16-lane group (fixed tree -> deterministic)
__device__ __forceinline__ float red16(float v) {
    v = dpp_add<0xB1>(v);    // quad_perm(1,0,3,2)
    v = dpp_add<0x4E>(v);    // quad_perm(2,3,0,1)
    v = dpp_add<0x141>(v);   // row_half_mirror
    v = dpp_add<0x140>(v);   // row_mirror
    return v;
}
__device__ __forceinline__ half8v cvt8(const float* p) {
    f32x4 a = *(const f32x4*)p;
    f32x4 b = *(const f32x4*)(p + 4);
    half8v r = {(_Float16)a[0], (_Float16)a[1], (_Float16)a[2], (_Float16)a[3],
                (_Float16)b[0], (_Float16)b[1], (_Float16)b[2], (_Float16)b[3]};
    return r;
}

// ---------------- Kernel 0: build all weight fragments ------------------
__global__ __launch_bounds__(64) void setup_kernel(
    const float* __restrict__ We1, const float* __restrict__ be1,
    const float* __restrict__ We2, const float* __restrict__ be2,
    const float* __restrict__ Wh1, const float* __restrict__ bh1,
    const float* __restrict__ Wh2, const float* __restrict__ bh2,
    half8v* __restrict__ frags)
{
    const int bid = blockIdx.x;
    const int l = threadIdx.x;
    const int c16 = l & 15, g = l >> 4;

    if (bid >= NFRAG) {
        // K16 tail frags for edge We2: k = 64 + 4g + jj, bias(be2) at k=72
        half4v* tail = (half4v*)(frags + NFRAG * 64);
        const int nt = bid - NFRAG;
        const int n = nt * 16 + c16;
        half4v f = {};
        if (n < C_) {
            #pragma unroll
            for (int jj = 0; jj < 4; ++jj) {
                int k = 64 + 4 * g + jj;
                float w = 0.f;
                if (k < C_) w = We2[k * C_ + n];
                else if (k == C_) w = be2[n];
                f[jj] = (_Float16)w;
            }
        }
        tail[nt * 64 + l] = f;
        return;
    }

    const float* W;
    const float* bias;
    int kmax, rel;
    if (bid < 15)      { W = We2;            bias = be2;     kmax = 72;  rel = bid; }
    else if (bid < 30) { W = We1;            bias = nullptr; kmax = 72;  rel = bid - 15; }
    else if (bid < 45) { W = We1 + 72 * C_;  bias = be1;     kmax = 72;  rel = bid - 30; }
    else if (bid < 70) { W = Wh1;            bias = bh1;     kmax = 144; rel = bid - 45; }
    else               { W = Wh2;            bias = bh2;     kmax = 72;  rel = bid - 70; }
    const int kt = rel / 5, nt = rel - 5 * kt;
    const int n = nt * 16 + c16;

    half8v f = {};
    if (n < C_) {
        #pragma unroll
        for (int jj = 0; jj < 8; ++jj) {
            int k = kt * 32 + g * 8 + jj;
            float w = 0.f;
            if (k < kmax) w = W[k * C_ + n];
            else if (k == kmax && bias) w = bias[n];
            f[jj] = (_Float16)w;
        }
    }
    frags[bid * 64 + l] = f;
}

// ---------------- Kernel 1: pre (MFMA, sel split across grid) -----------
__global__ __launch_bounds__(64) void pre_kernel(
    const float* __restrict__ h, const half8v* __restrict__ frags,
    _Float16* __restrict__ Ah, _Float16* __restrict__ Bch)
{
    const int l = threadIdx.x, c16 = l & 15, g = l >> 4;
    const int sel = blockIdx.x & 1;
    const int m0 = (blockIdx.x >> 1) * 16;

    const float* hrow = h + (m0 + c16) * C_;
    half8v a0 = cvt8(hrow + g * 8);
    half8v a1 = cvt8(hrow + 32 + g * 8);
    half8v a2 = {};
    if (g == 0) a2 = cvt8(hrow + 64);
    else if (g == 1) a2[0] = (_Float16)1.0f;   // bias row k=72

    const half8v* F = frags + (sel ? FRAG_WE1B : FRAG_WE1A);
    f32x4 acc[5] = {};
    #pragma unroll
    for (int kt = 0; kt < 3; ++kt) {
        half8v a = (kt == 0) ? a0 : (kt == 1 ? a1 : a2);
        #pragma unroll
        for (int nt = 0; nt < 5; ++nt)
            acc[nt] = __builtin_amdgcn_mfma_f32_16x16x32_f16(a, F[(kt * 5 + nt) * 64 + l], acc[nt], 0, 0, 0);
    }
    _Float16* dst = sel ? Bch : Ah;
    #pragma unroll
    for (int nt = 0; nt < 5; ++nt) {
        int n = nt * 16 + c16;
        if (n < C_) {
            #pragma unroll
            for (int r = 0; r < 4; ++r)
                dst[(m0 + 4 * g + r) * PADC + n] = (_Float16)acc[nt][r];
        }
    }
}

// ---------------- Kernel 2: edge MLP (R7 structure, 5 waves/EU) ---------
__global__ __launch_bounds__(256)
__attribute__((amdgpu_waves_per_eu(5)))
void edge_kernel(
    const float* __restrict__ x, const _Float16* __restrict__ Ah,
    const _Float16* __restrict__ Bch, const float* __restrict__ We1,
    const half8v* __restrict__ frags,
    const float* __restrict__ Wm, const float* __restrict__ bm,
    const float* __restrict__ Wx,
    float* __restrict__ wm_out, float* __restrict__ xacc_out)
{
    __shared__ __align__(16) _Float16 A_s[IT][PADC];
    __shared__ __align__(16) _Float16 Bc_s[P_][BCS];
    __shared__ __align__(16) float xj_s[P_][4];
    __shared__ __align__(16) _Float16 w1_s[PADC], w2_s[PADC];

    const int b  = blockIdx.x >> 5;
    const int it = blockIdx.x & 31;
    const int t  = threadIdx.x;
    const int wv = t >> 6;
    const int l  = t & 63;
    const int c16 = l & 15;
    const int g   = l >> 4;

    // ---- stage to LDS ----
    {
        const unsigned int* Asrc = (const unsigned int*)(Ah + (b * P_ + it * IT) * PADC);
        for (int idx = t; idx < IT * PADC / 2; idx += 256)
            ((unsigned int*)A_s)[idx] = Asrc[idx];
        for (int cidx = t; cidx < P_ * 10; cidx += 256) {
            int r = cidx / 10, c = cidx - r * 10;
            *(u32x4*)&Bc_s[r][c * 8] = ((const u32x4*)(Bch + (b * P_ + r) * PADC))[c];
        }
        for (int idx = t; idx < P_ * 4; idx += 256)
            ((float*)xj_s)[idx] = x[b * P_ * 4 + idx];
        if (t < 160) {
            int hs = t >= 80;
            int c = t - hs * 80;
            float wv_ = (c < C_) ? We1[(144 + hs) * C_ + c] : 0.f;
            (hs ? w2_s : w1_s)[c] = (_Float16)wv_;
        }
    }
    __syncthreads();

    // ---- We2 fragments: 2x K32 + 1x K16 tail ----
    half8v Wf[2][5];
    #pragma unroll
    for (int kt = 0; kt < 2; ++kt)
        #pragma unroll
        for (int nt = 0; nt < 5; ++nt)
            Wf[kt][nt] = frags[FRAG_WE2 + (kt * 5 + nt) * 64 + l];
    half4v Wf2[5];
    {
        const half4v* tail = (const half4v*)(frags + NFRAG * 64);
        #pragma unroll
        for (int nt = 0; nt < 5; ++nt)
            Wf2[nt] = tail[nt * 64 + l];
    }

    // per-lane channel weights (ch = nt*16 + 4g + r), f32 pair {Wm, Wx}
    f32x2 WmWx[5][4];
    #pragma unroll
    for (int nt = 0; nt < 5; ++nt)
        #pragma unroll
        for (int r = 0; r < 4; ++r) {
            int ch = nt * 16 + 4 * g + r;
            bool ok = ch < C_;
            WmWx[nt][r][0] = ok ? Wm[ch] : 0.f;
            WmWx[nt][r][1] = ok ? Wx[ch] : 0.f;
        }
    const float bm0 = bm[0];
    const f32x4 zero4 = {0.f, 0.f, 0.f, 0.f};

    const int iloc = wv;                   // wave owns one i-row
    const int i = it * IT + iloc;
    const int node_i = b * P_ + i;
    const f32x4 xi = *(const f32x4*)&xj_s[i][0];

    f32x4 wmacc[5] = {};
    f32x4 xacc = {0.f, 0.f, 0.f, 0.f};

    #pragma unroll 1
    for (int jt = 0; jt < 8; ++jt) {
        // ---- phase A: this lane's m1^T B-fragment chunks ----
        const int j = jt * 16 + c16;
        const f32x4 xjv = *(const f32x4*)&xj_s[j][0];
        float d0 = xi[0] - xjv[0], d1 = xi[1] - xjv[1];
        float d2 = xi[2] - xjv[2], d3 = xi[3] - xjv[3];
        float nn = d0 * d0 - d1 * d1 - d2 * d2 - d3 * d3;
        float pp = xi[0] * xjv[0] - xi[1] * xjv[1] - xi[2] * xjv[2] - xi[3] * xjv[3];
        _Float16 nh = (_Float16)psi_f(nn);
        _Float16 ph = (_Float16)psi_f(pp);
        half8v n8 = {nh, nh, nh, nh, nh, nh, nh, nh};
        half8v p8 = {ph, ph, ph, ph, ph, ph, ph, ph};
        half8v zero8 = {};

        auto chunk = [&](int k) -> half8v {
            half8v v = *(const half8v*)&A_s[iloc][k] + *(const half8v*)&Bc_s[j][k];
            v = __builtin_elementwise_fma(*(const half8v*)&w1_s[k], n8, v);
            v = __builtin_elementwise_fma(*(const half8v*)&w2_s[k], p8, v);
            return __builtin_elementwise_max(v, zero8);
        };
        half8v af0 = chunk(g * 8);
        half8v af1 = chunk(32 + g * 8);

        // K16 tail: k = 64 + 4g + jj; g==2 carries be2 bias row (k=72)
        half4v af2 = {};
        if (g < 2) {
            const int k = 64 + 4 * g;
            half4v n4 = {nh, nh, nh, nh};
            half4v p4 = {ph, ph, ph, ph};
            half4v zero4h = {};
            half4v v = *(const half4v*)&A_s[iloc][k] + *(const half4v*)&Bc_s[j][k];
            v = __builtin_elementwise_fma(*(const half4v*)&w1_s[k], n4, v);
            v = __builtin_elementwise_fma(*(const half4v*)&w2_s[k], p4, v);
            af2 = __builtin_elementwise_max(v, zero4h);
        } else if (g == 2) {
            af2[0] = (_Float16)1.0f;
        }

        // ---- phase B: D[ch][edge] = We2^T @ m1^T ----
        f32x4 acc[5] = {};
        #pragma unroll
        for (int nt = 0; nt < 5; ++nt)
            acc[nt] = __builtin_amdgcn_mfma_f32_16x16x32_f16(Wf[0][nt], af0, acc[nt], 0, 0, 0);
        #pragma unroll
        for (int nt = 0; nt < 5; ++nt)
            acc[nt] = __builtin_amdgcn_mfma_f32_16x16x32_f16(Wf[1][nt], af1, acc[nt], 0, 0, 0);
        #pragma unroll
        for (int nt = 0; nt < 5; ++nt)
            acc[nt] = __builtin_amdgcn_mfma_f32_16x16x16f16(Wf2[nt], af2, acc[nt], 0, 0, 0);

        // ---- phase C: lane owns edge j; channels packed f32x2 dots ----
        f32x2 wdpd = {0.f, 0.f};
        #pragma unroll
        for (int nt = 0; nt < 5; ++nt) {
            f32x4 m2q = __builtin_elementwise_max(acc[nt], zero4);
            acc[nt] = m2q;
            #pragma unroll
            for (int r = 0; r < 4; ++r) {
                f32x2 vv = {m2q[r], m2q[r]};
                wdpd = __builtin_elementwise_fma(vv, WmWx[nt][r], wdpd);
            }
        }
        // reduce across the 4 g-groups (lanes xor 16, 32)
        {
            f32x2 s;
            s[0] = __shfl_xor(wdpd[0], 16, 64);
            s[1] = __shfl_xor(wdpd[1], 16, 64);
            wdpd += s;
            s[0] = __shfl_xor(wdpd[0], 32, 64);
            s[1] = __shfl_xor(wdpd[1], 32, 64);
            wdpd += s;
        }
        float w_ = __builtin_amdgcn_rcpf(1.f + __expf(-(wdpd[0] + bm0)));
        f32x4 w4 = {w_, w_, w_, w_};
        #pragma unroll
        for (int nt = 0; nt < 5; ++nt)
            wmacc[nt] = __builtin_elementwise_fma(w4, acc[nt], wmacc[nt]);
        f32x4 pd4 = {wdpd[1], wdpd[1], wdpd[1], wdpd[1]};
        xacc = __builtin_elementwise_fma(pd4, xjv, xacc);
    } // jt

    // ---- finalize: sum across the 16 edge-lanes of each row ----
    #pragma unroll
    for (int nt = 0; nt < 5; ++nt)
        #pragma unroll
        for (int r = 0; r < 4; ++r)
            wmacc[nt][r] = red16(wmacc[nt][r]);
    #pragma unroll
    for (int q = 0; q < 4; ++q) xacc[q] = red16(xacc[q]);

    if (c16 == 0) {
        #pragma unroll
        for (int nt = 0; nt < 5; ++nt)
            #pragma unroll
            for (int r = 0; r < 4; ++r) {
                int ch = nt * 16 + 4 * g + r;
                if (ch < C_) wm_out[node_i * C_ + ch] = wmacc[nt][r];
            }
    }
    if (l == 0)
        *(f32x4*)&xacc_out[node_i * 4] = xacc;
}

// ---------------- Kernel 3: node MLP (chained MFMAs, frag loads) --------
__global__ __launch_bounds__(64) void node_kernel(
    const float* __restrict__ x, const float* __restrict__ h,
    const half8v* __restrict__ frags,
    const float* __restrict__ wm, const float* __restrict__ xacc,
    float* __restrict__ hout, float* __restrict__ xout)
{
    __shared__ _Float16 g_s[16][BCS];
    const int l = threadIdx.x, c16 = l & 15, g = l >> 4;
    const int m0 = blockIdx.x * 16;

    const float* hrow  = h  + (m0 + c16) * C_;
    const float* wmrow = wm + (m0 + c16) * C_;

    // ---- GEMM1: [h|wm|1] (K=160) @ Wh1(+bh1 row 144) ----
    half8v a[5];
    #pragma unroll
    for (int kt = 0; kt < 5; ++kt) {
        int k = kt * 32 + g * 8;
        half8v v = {};
        if (k < C_) v = cvt8(hrow + k);
        else if (k < 144) v = cvt8(wmrow + (k - C_));
        else if (k == 144) v[0] = (_Float16)1.0f;
        a[kt] = v;
    }
    f32x4 acc1[5] = {};
    #pragma unroll
    for (int kt = 0; kt < 5; ++kt)
        #pragma unroll
        for (int nt = 0; nt < 5; ++nt)
            acc1[nt] = __builtin_amdgcn_mfma_f32_16x16x32_f16(
                a[kt], frags[FRAG_WH1 + (kt * 5 + nt) * 64 + l], acc1[nt], 0, 0, 0);

    // relu -> wave-local LDS transpose (D layout -> A-fragment layout)
    #pragma unroll
    for (int nt = 0; nt < 5; ++nt) {
        int n = nt * 16 + c16;
        #pragma unroll
        for (int r = 0; r < 4; ++r)
            g_s[4 * g + r][n] = (_Float16)fmaxf(acc1[nt][r], 0.f);
    }
    half8v b0 = *(const half8v*)&g_s[c16][g * 8];
    half8v b1 = *(const half8v*)&g_s[c16][32 + g * 8];
    half8v b2 = {};
    if (g == 0) b2 = *(const half8v*)&g_s[c16][64];
    else if (g == 1) b2[0] = (_Float16)1.0f;   // bh2 bias row k=72

    // ---- GEMM2: g (K=96) @ Wh2(+bh2 row 72) ----
    f32x4 acc2[5] = {};
    #pragma unroll
    for (int kt = 0; kt < 3; ++kt) {
        half8v aa = (kt == 0) ? b0 : (kt == 1 ? b1 : b2);
        #pragma unroll
        for (int nt = 0; nt < 5; ++nt)
            acc2[nt] = __builtin_amdgcn_mfma_f32_16x16x32_f16(
                aa, frags[FRAG_WH2 + (kt * 5 + nt) * 64 + l], acc2[nt], 0, 0, 0);
    }
    #pragma unroll
    for (int nt = 0; nt < 5; ++nt) {
        int n = nt * 16 + c16;
        if (n < C_) {
            #pragma unroll
            for (int r = 0; r < 4; ++r) {
                int row = m0 + 4 * g + r;
                hout[row * C_ + n] = h[row * C_ + n] + acc2[nt][r];
            }
        }
    }
    {
        int row = m0 + (l >> 2), d = l & 3;
        xout[row * 4 + d] = x[row * 4 + d] + 0.005f * (xacc[row * 4 + d] * (1.0f / 128.f));
    }
}

extern "C" void kernel_launch(void* const* d_in, const int* in_sizes, int n_in,
                              void* d_out, int out_size, void* d_ws, size_t ws_size,
                              hipStream_t stream) {
    const float* x   = (const float*)d_in[0];
    const float* h   = (const float*)d_in[1];
    const float* We1 = (const float*)d_in[2];
    const float* be1 = (const float*)d_in[3];
    const float* We2 = (const float*)d_in[4];
    const float* be2 = (const float*)d_in[5];
    const float* Wm  = (const float*)d_in[6];
    const float* bm  = (const float*)d_in[7];
    const float* Wh1 = (const float*)d_in[8];
    const float* bh1 = (const float*)d_in[9];
    const float* Wh2 = (const float*)d_in[10];
    const float* bh2 = (const float*)d_in[11];
    const float* Wx  = (const float*)d_in[12];

    const int NNODE = B_ * P_;                       // 8192
    _Float16* Ah  = (_Float16*)d_ws;                 // [8192][80] f16
    _Float16* Bch = Ah + NNODE * PADC;               // [8192][80] f16
    float* wm   = (float*)(Bch + NNODE * PADC);      // [8192][72] f32
    float* xacc = wm + NNODE * C_;                   // [8192][4]  f32
    half8v* frags = (half8v*)(xacc + NNODE * 4);     // 85 frags x 1KB + 5 tail x 0.5KB

    float* hout = (float*)d_out;                     // [8192][72]
    float* xout = hout + NNODE * C_;                 // [8192][4]

    setup_kernel<<<NFRAG + 5, 64, 0, stream>>>(We1, be1, We2, be2, Wh1, bh1, Wh2, bh2, frags);
    pre_kernel<<<NNODE / 16 * 2, 64, 0, stream>>>(h, frags, Ah, Bch);
    edge_kernel<<<B_ * 32, 256, 0, stream>>>(x, Ah, Bch, We1, frags,
                                             Wm, bm, Wx, wm, xacc);
    node_kernel<<<NNODE / 16, 64, 0, stream>>>(x, h, frags, wm, xacc, hout, xout);
}

// Round 11
// 64.030 us; speedup vs baseline: 4.1676x; 4.1676x over previous
//
#include <hip/hip_runtime.h>
#include <hip/hip_bf16.h>
#include <math.h>

#define B_ 64
#define P_ 128
#define C_ 72
#define PADC 80    // f16 global row stride for A/Bc
#define BCS 88     // LDS row stride in halfs (176B -> 2-way banks, free)
#define IT 4       // i-rows per edge block (1 per wave)

typedef __attribute__((ext_vector_type(8))) _Float16 half8v;
typedef __attribute__((ext_vector_type(4))) _Float16 half4v;
typedef __attribute__((ext_vector_type(4))) float f32x4;
typedef __attribute__((ext_vector_type(2))) float f32x2;
typedef __attribute__((ext_vector_type(4))) unsigned int u32x4;

// precomputed weight-fragment table (units: half8v, 64 per fragment)
#define FRAG_WE2  0          // We2 kt=0,1 (K32), 15 frag slots
#define FRAG_WE1A (15 * 64)  // We1 rows 0..71, 15 frags
#define FRAG_WE1B (30 * 64)  // We1 rows 72..143 (+be1 @k=72), 15 frags
#define FRAG_WH1  (45 * 64)  // Wh1 (+bh1 @k=144), 25 frags
#define FRAG_WH2  (70 * 64)  // Wh2 (+bh2 @k=72), 15 frags
#define NFRAG 85             // + 5 K16-tail frags (half4v) appended

__device__ __forceinline__ float psi_f(float v) {
    float a = fabsf(v);
    return copysignf(__logf(1.0f + a), v);
}
template <int CTRL>
__device__ __forceinline__ float dpp_add(float v) {
    int s = __builtin_amdgcn_update_dpp(0, __builtin_bit_cast(int, v), CTRL, 0xF, 0xF, true);
    return v + __builtin_bit_cast(float, s);
}
// full sum across each 16-lane group (fixed tree -> deterministic)
__device__ __forceinline__ float red16(float v) {
    v = dpp_add<0xB1>(v);    // quad_perm(1,0,3,2)
    v = dpp_add<0x4E>(v);    // quad_perm(2,3,0,1)
    v = dpp_add<0x141>(v);   // row_half_mirror
    v = dpp_add<0x140>(v);   // row_mirror
    return v;
}
__device__ __forceinline__ half8v cvt8(const float* p) {
    f32x4 a = *(const f32x4*)p;
    f32x4 b = *(const f32x4*)(p + 4);
    half8v r = {(_Float16)a[0], (_Float16)a[1], (_Float16)a[2], (_Float16)a[3],
                (_Float16)b[0], (_Float16)b[1], (_Float16)b[2], (_Float16)b[3]};
    return r;
}

// ---------------- Kernel 0: build all weight fragments ------------------
__global__ __launch_bounds__(64) void setup_kernel(
    const float* __restrict__ We1, const float* __restrict__ be1,
    const float* __restrict__ We2, const float* __restrict__ be2,
    const float* __restrict__ Wh1, const float* __restrict__ bh1,
    const float* __restrict__ Wh2, const float* __restrict__ bh2,
    half8v* __restrict__ frags)
{
    const int bid = blockIdx.x;
    const int l = threadIdx.x;
    const int c16 = l & 15, g = l >> 4;

    if (bid >= NFRAG) {
        // K16 tail frags for edge We2: k = 64 + 4g + jj, bias(be2) at k=72
        half4v* tail = (half4v*)(frags + NFRAG * 64);
        const int nt = bid - NFRAG;
        const int n = nt * 16 + c16;
        half4v f = {};
        if (n < C_) {
            #pragma unroll
            for (int jj = 0; jj < 4; ++jj) {
                int k = 64 + 4 * g + jj;
                float w = 0.f;
                if (k < C_) w = We2[k * C_ + n];
                else if (k == C_) w = be2[n];
                f[jj] = (_Float16)w;
            }
        }
        tail[nt * 64 + l] = f;
        return;
    }

    const float* W;
    const float* bias;
    int kmax, rel;
    if (bid < 15)      { W = We2;            bias = be2;     kmax = 72;  rel = bid; }
    else if (bid < 30) { W = We1;            bias = nullptr; kmax = 72;  rel = bid - 15; }
    else if (bid < 45) { W = We1 + 72 * C_;  bias = be1;     kmax = 72;  rel = bid - 30; }
    else if (bid < 70) { W = Wh1;            bias = bh1;     kmax = 144; rel = bid - 45; }
    else               { W = Wh2;            bias = bh2;     kmax = 72;  rel = bid - 70; }
    const int kt = rel / 5, nt = rel - 5 * kt;
    const int n = nt * 16 + c16;

    half8v f = {};
    if (n < C_) {
        #pragma unroll
        for (int jj = 0; jj < 8; ++jj) {
            int k = kt * 32 + g * 8 + jj;
            float w = 0.f;
            if (k < kmax) w = W[k * C_ + n];
            else if (k == kmax && bias) w = bias[n];
            f[jj] = (_Float16)w;
        }
    }
    frags[bid * 64 + l] = f;
}

// ---------------- Kernel 1: pre (MFMA, sel split across grid) -----------
__global__ __launch_bounds__(64) void pre_kernel(
    const float* __restrict__ h, const half8v* __restrict__ frags,
    _Float16* __restrict__ Ah, _Float16* __restrict__ Bch)
{
    const int l = threadIdx.x, c16 = l & 15, g = l >> 4;
    const int sel = blockIdx.x & 1;
    const int m0 = (blockIdx.x >> 1) * 16;

    const float* hrow = h + (m0 + c16) * C_;
    half8v a0 = cvt8(hrow + g * 8);
    half8v a1 = cvt8(hrow + 32 + g * 8);
    half8v a2 = {};
    if (g == 0) a2 = cvt8(hrow + 64);
    else if (g == 1) a2[0] = (_Float16)1.0f;   // bias row k=72

    const half8v* F = frags + (sel ? FRAG_WE1B : FRAG_WE1A);
    f32x4 acc[5] = {};
    #pragma unroll
    for (int kt = 0; kt < 3; ++kt) {
        half8v a = (kt == 0) ? a0 : (kt == 1 ? a1 : a2);
        #pragma unroll
        for (int nt = 0; nt < 5; ++nt)
            acc[nt] = __builtin_amdgcn_mfma_f32_16x16x32_f16(a, F[(kt * 5 + nt) * 64 + l], acc[nt], 0, 0, 0);
    }
    _Float16* dst = sel ? Bch : Ah;
    #pragma unroll
    for (int nt = 0; nt < 5; ++nt) {
        int n = nt * 16 + c16;
        if (n < C_) {
            #pragma unroll
            for (int r = 0; r < 4; ++r)
                dst[(m0 + 4 * g + r) * PADC + n] = (_Float16)acc[nt][r];
        }
    }
}

// ---------------- Kernel 2: edge MLP (IT=4, K16 tail, (256,2)) ----------
__global__ __launch_bounds__(256, 2) void edge_kernel(
    const float* __restrict__ x, const _Float16* __restrict__ Ah,
    const _Float16* __restrict__ Bch, const float* __restrict__ We1,
    const half8v* __restrict__ frags,
    const float* __restrict__ Wm, const float* __restrict__ bm,
    const float* __restrict__ Wx,
    float* __restrict__ wm_out, float* __restrict__ xacc_out)
{
    __shared__ __align__(16) _Float16 A_s[IT][PADC];
    __shared__ __align__(16) _Float16 Bc_s[P_][BCS];
    __shared__ __align__(16) float xj_s[P_][4];
    __shared__ __align__(16) _Float16 w1_s[PADC], w2_s[PADC];

    const int b  = blockIdx.x >> 5;
    const int it = blockIdx.x & 31;
    const int t  = threadIdx.x;
    const int wv = t >> 6;
    const int l  = t & 63;
    const int c16 = l & 15;
    const int g   = l >> 4;

    // ---- stage to LDS ----
    {
        const unsigned int* Asrc = (const unsigned int*)(Ah + (b * P_ + it * IT) * PADC);
        for (int idx = t; idx < IT * PADC / 2; idx += 256)
            ((unsigned int*)A_s)[idx] = Asrc[idx];
        for (int cidx = t; cidx < P_ * 10; cidx += 256) {
            int r = cidx / 10, c = cidx - r * 10;
            *(u32x4*)&Bc_s[r][c * 8] = ((const u32x4*)(Bch + (b * P_ + r) * PADC))[c];
        }
        for (int idx = t; idx < P_ * 4; idx += 256)
            ((float*)xj_s)[idx] = x[b * P_ * 4 + idx];
        if (t < 160) {
            int hs = t >= 80;
            int c = t - hs * 80;
            float wv_ = (c < C_) ? We1[(144 + hs) * C_ + c] : 0.f;
            (hs ? w2_s : w1_s)[c] = (_Float16)wv_;
        }
    }
    __syncthreads();

    // ---- We2 fragments: 2x K32 + 1x K16 tail ----
    half8v Wf[2][5];
    #pragma unroll
    for (int kt = 0; kt < 2; ++kt)
        #pragma unroll
        for (int nt = 0; nt < 5; ++nt)
            Wf[kt][nt] = frags[FRAG_WE2 + (kt * 5 + nt) * 64 + l];
    half4v Wf2[5];
    {
        const half4v* tail = (const half4v*)(frags + NFRAG * 64);
        #pragma unroll
        for (int nt = 0; nt < 5; ++nt)
            Wf2[nt] = tail[nt * 64 + l];
    }

    // per-lane channel weights (ch = nt*16 + 4g + r), f32 pair {Wm, Wx}
    f32x2 WmWx[5][4];
    #pragma unroll
    for (int nt = 0; nt < 5; ++nt)
        #pragma unroll
        for (int r = 0; r < 4; ++r) {
            int ch = nt * 16 + 4 * g + r;
            bool ok = ch < C_;
            WmWx[nt][r][0] = ok ? Wm[ch] : 0.f;
            WmWx[nt][r][1] = ok ? Wx[ch] : 0.f;
        }
    const float bm0 = bm[0];
    const f32x4 zero4 = {0.f, 0.f, 0.f, 0.f};

    const int iloc = wv;                   // wave owns one i-row
    const int i = it * IT + iloc;
    const int node_i = b * P_ + i;
    const f32x4 xi = *(const f32x4*)&xj_s[i][0];

    f32x4 wmacc[5] = {};
    f32x4 xacc = {0.f, 0.f, 0.f, 0.f};

    #pragma unroll 1
    for (int jt = 0; jt < 8; ++jt) {
        // ---- phase A: this lane's m1^T B-fragment chunks ----
        const int j = jt * 16 + c16;
        const f32x4 xjv = *(const f32x4*)&xj_s[j][0];
        float d0 = xi[0] - xjv[0], d1 = xi[1] - xjv[1];
        float d2 = xi[2] - xjv[2], d3 = xi[3] - xjv[3];
        float nn = d0 * d0 - d1 * d1 - d2 * d2 - d3 * d3;
        float pp = xi[0] * xjv[0] - xi[1] * xjv[1] - xi[2] * xjv[2] - xi[3] * xjv[3];
        _Float16 nh = (_Float16)psi_f(nn);
        _Float16 ph = (_Float16)psi_f(pp);
        half8v n8 = {nh, nh, nh, nh, nh, nh, nh, nh};
        half8v p8 = {ph, ph, ph, ph, ph, ph, ph, ph};
        half8v zero8 = {};

        auto chunk = [&](int k) -> half8v {
            half8v v = *(const half8v*)&A_s[iloc][k] + *(const half8v*)&Bc_s[j][k];
            v = __builtin_elementwise_fma(*(const half8v*)&w1_s[k], n8, v);
            v = __builtin_elementwise_fma(*(const half8v*)&w2_s[k], p8, v);
            return __builtin_elementwise_max(v, zero8);
        };
        half8v af0 = chunk(g * 8);
        half8v af1 = chunk(32 + g * 8);

        // K16 tail: k = 64 + 4g + jj; g==2 carries be2 bias row (k=72)
        half4v af2 = {};
        if (g < 2) {
            const int k = 64 + 4 * g;
            half4v n4 = {nh, nh, nh, nh};
            half4v p4 = {ph, ph, ph, ph};
            half4v zero4h = {};
            half4v v = *(const half4v*)&A_s[iloc][k] + *(const half4v*)&Bc_s[j][k];
            v = __builtin_elementwise_fma(*(const half4v*)&w1_s[k], n4, v);
            v = __builtin_elementwise_fma(*(const half4v*)&w2_s[k], p4, v);
            af2 = __builtin_elementwise_max(v, zero4h);
        } else if (g == 2) {
            af2[0] = (_Float16)1.0f;
        }

        // ---- phase B: D[ch][edge] = We2^T @ m1^T (2x K32 + 1x K16) ----
        f32x4 acc[5] = {};
        #pragma unroll
        for (int nt = 0; nt < 5; ++nt)
            acc[nt] = __builtin_amdgcn_mfma_f32_16x16x32_f16(Wf[0][nt], af0, acc[nt], 0, 0, 0);
        #pragma unroll
        for (int nt = 0; nt < 5; ++nt)
            acc[nt] = __builtin_amdgcn_mfma_f32_16x16x32_f16(Wf[1][nt], af1, acc[nt], 0, 0, 0);
        #pragma unroll
        for (int nt = 0; nt < 5; ++nt)
            acc[nt] = __builtin_amdgcn_mfma_f32_16x16x16f16(Wf2[nt], af2, acc[nt], 0, 0, 0);

        // ---- phase C: lane owns edge j; channels packed f32x2 dots ----
        f32x2 wdpd = {0.f, 0.f};
        #pragma unroll
        for (int nt = 0; nt < 5; ++nt) {
            f32x4 m2q = __builtin_elementwise_max(acc[nt], zero4);
            acc[nt] = m2q;
            #pragma unroll
            for (int r = 0; r < 4; ++r) {
                f32x2 vv = {m2q[r], m2q[r]};
                wdpd = __builtin_elementwise_fma(vv, WmWx[nt][r], wdpd);
            }
        }
        // reduce across the 4 g-groups (lanes xor 16, 32)
        {
            f32x2 s;
            s[0] = __shfl_xor(wdpd[0], 16, 64);
            s[1] = __shfl_xor(wdpd[1], 16, 64);
            wdpd += s;
            s[0] = __shfl_xor(wdpd[0], 32, 64);
            s[1] = __shfl_xor(wdpd[1], 32, 64);
            wdpd += s;
        }
        float w_ = __builtin_amdgcn_rcpf(1.f + __expf(-(wdpd[0] + bm0)));
        f32x4 w4 = {w_, w_, w_, w_};
        #pragma unroll
        for (int nt = 0; nt < 5; ++nt)
            wmacc[nt] = __builtin_elementwise_fma(w4, acc[nt], wmacc[nt]);
        f32x4 pd4 = {wdpd[1], wdpd[1], wdpd[1], wdpd[1]};
        xacc = __builtin_elementwise_fma(pd4, xjv, xacc);
    } // jt

    // ---- finalize: sum across the 16 edge-lanes of each row ----
    #pragma unroll
    for (int nt = 0; nt < 5; ++nt)
        #pragma unroll
        for (int r = 0; r < 4; ++r)
            wmacc[nt][r] = red16(wmacc[nt][r]);
    #pragma unroll
    for (int q = 0; q < 4; ++q) xacc[q] = red16(xacc[q]);

    if (c16 == 0) {
        #pragma unroll
        for (int nt = 0; nt < 5; ++nt)
            #pragma unroll
            for (int r = 0; r < 4; ++r) {
                int ch = nt * 16 + 4 * g + r;
                if (ch < C_) wm_out[node_i * C_ + ch] = wmacc[nt][r];
            }
    }
    if (l == 0)
        *(f32x4*)&xacc_out[node_i * 4] = xacc;
}

// ---------------- Kernel 3: node MLP (chained MFMAs, frag loads) --------
__global__ __launch_bounds__(64) void node_kernel(
    const float* __restrict__ x, const float* __restrict__ h,
    const half8v* __restrict__ frags,
    const float* __restrict__ wm, const float* __restrict__ xacc,
    float* __restrict__ hout, float* __restrict__ xout)
{
    __shared__ _Float16 g_s[16][BCS];
    const int l = threadIdx.x, c16 = l & 15, g = l >> 4;
    const int m0 = blockIdx.x * 16;

    const float* hrow  = h  + (m0 + c16) * C_;
    const float* wmrow = wm + (m0 + c16) * C_;

    // ---- GEMM1: [h|wm|1] (K=160) @ Wh1(+bh1 row 144) ----
    half8v a[5];
    #pragma unroll
    for (int kt = 0; kt < 5; ++kt) {
        int k = kt * 32 + g * 8;
        half8v v = {};
        if (k < C_) v = cvt8(hrow + k);
        else if (k < 144) v = cvt8(wmrow + (k - C_));
        else if (k == 144) v[0] = (_Float16)1.0f;
        a[kt] = v;
    }
    f32x4 acc1[5] = {};
    #pragma unroll
    for (int kt = 0; kt < 5; ++kt)
        #pragma unroll
        for (int nt = 0; nt < 5; ++nt)
            acc1[nt] = __builtin_amdgcn_mfma_f32_16x16x32_f16(
                a[kt], frags[FRAG_WH1 + (kt * 5 + nt) * 64 + l], acc1[nt], 0, 0, 0);

    // relu -> wave-local LDS transpose (D layout -> A-fragment layout)
    #pragma unroll
    for (int nt = 0; nt < 5; ++nt) {
        int n = nt * 16 + c16;
        #pragma unroll
        for (int r = 0; r < 4; ++r)
            g_s[4 * g + r][n] = (_Float16)fmaxf(acc1[nt][r], 0.f);
    }
    half8v b0 = *(const half8v*)&g_s[c16][g * 8];
    half8v b1 = *(const half8v*)&g_s[c16][32 + g * 8];
    half8v b2 = {};
    if (g == 0) b2 = *(const half8v*)&g_s[c16][64];
    else if (g == 1) b2[0] = (_Float16)1.0f;   // bh2 bias row k=72

    // ---- GEMM2: g (K=96) @ Wh2(+bh2 row 72) ----
    f32x4 acc2[5] = {};
    #pragma unroll
    for (int kt = 0; kt < 3; ++kt) {
        half8v aa = (kt == 0) ? b0 : (kt == 1 ? b1 : b2);
        #pragma unroll
        for (int nt = 0; nt < 5; ++nt)
            acc2[nt] = __builtin_amdgcn_mfma_f32_16x16x32_f16(
                aa, frags[FRAG_WH2 + (kt * 5 + nt) * 64 + l], acc2[nt], 0, 0, 0);
    }
    #pragma unroll
    for (int nt = 0; nt < 5; ++nt) {
        int n = nt * 16 + c16;
        if (n < C_) {
            #pragma unroll
            for (int r = 0; r < 4; ++r) {
                int row = m0 + 4 * g + r;
                hout[row * C_ + n] = h[row * C_ + n] + acc2[nt][r];
            }
        }
    }
    {
        int row = m0 + (l >> 2), d = l & 3;
        xout[row * 4 + d] = x[row * 4 + d] + 0.005f * (xacc[row * 4 + d] * (1.0f / 128.f));
    }
}

extern "C" void kernel_launch(void* const* d_in, const int* in_sizes, int n_in,
                              void* d_out, int out_size, void* d_ws, size_t ws_size,
                              hipStream_t stream) {
    const float* x   = (const float*)d_in[0];
    const float* h   = (const float*)d_in[1];
    const float* We1 = (const float*)d_in[2];
    const float* be1 = (const float*)d_in[3];
    const float* We2 = (const float*)d_in[4];
    const float* be2 = (const float*)d_in[5];
    const float* Wm  = (const float*)d_in[6];
    const float* bm  = (const float*)d_in[7];
    const float* Wh1 = (const float*)d_in[8];
    const float* bh1 = (const float*)d_in[9];
    const float* Wh2 = (const float*)d_in[10];
    const float* bh2 = (const float*)d_in[11];
    const float* Wx  = (const float*)d_in[12];

    const int NNODE = B_ * P_;                       // 8192
    _Float16* Ah  = (_Float16*)d_ws;                 // [8192][80] f16
    _Float16* Bch = Ah + NNODE * PADC;               // [8192][80] f16
    float* wm   = (float*)(Bch + NNODE * PADC);      // [8192][72] f32
    float* xacc = wm + NNODE * C_;                   // [8192][4]  f32
    half8v* frags = (half8v*)(xacc + NNODE * 4);     // 85 frags x 1KB + 5 tail x 0.5KB

    float* hout = (float*)d_out;                     // [8192][72]
    float* xout = hout + NNODE * C_;                 // [8192][4]

    setup_kernel<<<NFRAG + 5, 64, 0, stream>>>(We1, be1, We2, be2, Wh1, bh1, Wh2, bh2, frags);
    pre_kernel<<<NNODE / 16 * 2, 64, 0, stream>>>(h, frags, Ah, Bch);
    edge_kernel<<<B_ * 32, 256, 0, stream>>>(x, Ah, Bch, We1, frags,
                                             Wm, bm, Wx, wm, xacc);
    node_kernel<<<NNODE / 16, 64, 0, stream>>>(x, h, frags, wm, xacc, hout, xout);
}

// Round 12
// 60.302 us; speedup vs baseline: 4.4252x; 1.0618x over previous
//
#include <hip/hip_runtime.h>
#include <hip/hip_bf16.h>
#include <math.h>

#define B_ 64
#define P_ 128
#define C_ 72
#define PADC 80    // f16 global row stride for Ah
#define IT 4       // i-rows per edge block (1 per wave)

typedef __attribute__((ext_vector_type(8))) _Float16 half8v;
typedef __attribute__((ext_vector_type(4))) _Float16 half4v;
typedef __attribute__((ext_vector_type(4))) float f32x4;
typedef __attribute__((ext_vector_type(2))) float f32x2;

// precomputed weight-fragment table (units: half8v, 64 per fragment)
#define FRAG_WE2  0          // We2 kt=0,1 (K32), 15 frag slots
#define FRAG_WE1A (15 * 64)  // We1 rows 0..71, 15 frags
#define FRAG_WE1B (30 * 64)  // We1 rows 72..143 (+be1 @k=72), 15 frags
#define FRAG_WH1  (45 * 64)  // Wh1 (+bh1 @k=144), 25 frags
#define FRAG_WH2  (70 * 64)  // Wh2 (+bh2 @k=72), 15 frags
#define NFRAG 85             // + 5 K16-tail frags (half4v) appended

__device__ __forceinline__ float psi_f(float v) {
    float a = fabsf(v);
    return copysignf(__logf(1.0f + a), v);
}
template <int CTRL>
__device__ __forceinline__ float dpp_add(float v) {
    int s = __builtin_amdgcn_update_dpp(0, __builtin_bit_cast(int, v), CTRL, 0xF, 0xF, true);
    return v + __builtin_bit_cast(float, s);
}
// full sum across each 16-lane group (fixed tree -> deterministic)
__device__ __forceinline__ float red16(float v) {
    v = dpp_add<0xB1>(v);    // quad_perm(1,0,3,2)
    v = dpp_add<0x4E>(v);    // quad_perm(2,3,0,1)
    v = dpp_add<0x141>(v);   // row_half_mirror
    v = dpp_add<0x140>(v);   // row_mirror
    return v;
}
__device__ __forceinline__ half8v cvt8(const float* p) {
    f32x4 a = *(const f32x4*)p;
    f32x4 b = *(const f32x4*)(p + 4);
    half8v r = {(_Float16)a[0], (_Float16)a[1], (_Float16)a[2], (_Float16)a[3],
                (_Float16)b[0], (_Float16)b[1], (_Float16)b[2], (_Float16)b[3]};
    return r;
}
__device__ __forceinline__ half4v cvt4(const float* p) {
    f32x4 a = *(const f32x4*)p;
    half4v r = {(_Float16)a[0], (_Float16)a[1], (_Float16)a[2], (_Float16)a[3]};
    return r;
}

// ---------------- Kernel 0: build all weight fragments ------------------
__global__ __launch_bounds__(64) void setup_kernel(
    const float* __restrict__ We1, const float* __restrict__ be1,
    const float* __restrict__ We2, const float* __restrict__ be2,
    const float* __restrict__ Wh1, const float* __restrict__ bh1,
    const float* __restrict__ Wh2, const float* __restrict__ bh2,
    half8v* __restrict__ frags)
{
    const int bid = blockIdx.x;
    const int l = threadIdx.x;
    const int c16 = l & 15, g = l >> 4;

    if (bid >= NFRAG) {
        // K16 tail frags for edge We2: k = 64 + 4g + jj, bias(be2) at k=72
        half4v* tail = (half4v*)(frags + NFRAG * 64);
        const int nt = bid - NFRAG;
        const int n = nt * 16 + c16;
        half4v f = {};
        if (n < C_) {
            #pragma unroll
            for (int jj = 0; jj < 4; ++jj) {
                int k = 64 + 4 * g + jj;
                float w = 0.f;
                if (k < C_) w = We2[k * C_ + n];
                else if (k == C_) w = be2[n];
                f[jj] = (_Float16)w;
            }
        }
        tail[nt * 64 + l] = f;
        return;
    }

    const float* W;
    const float* bias;
    int kmax, rel;
    if (bid < 15)      { W = We2;            bias = be2;     kmax = 72;  rel = bid; }
    else if (bid < 30) { W = We1;            bias = nullptr; kmax = 72;  rel = bid - 15; }
    else if (bid < 45) { W = We1 + 72 * C_;  bias = be1;     kmax = 72;  rel = bid - 30; }
    else if (bid < 70) { W = Wh1;            bias = bh1;     kmax = 144; rel = bid - 45; }
    else               { W = Wh2;            bias = bh2;     kmax = 72;  rel = bid - 70; }
    const int kt = rel / 5, nt = rel - 5 * kt;
    const int n = nt * 16 + c16;

    half8v f = {};
    if (n < C_) {
        #pragma unroll
        for (int jj = 0; jj < 8; ++jj) {
            int k = kt * 32 + g * 8 + jj;
            float w = 0.f;
            if (k < kmax) w = W[k * C_ + n];
            else if (k == kmax && bias) w = bias[n];
            f[jj] = (_Float16)w;
        }
    }
    frags[bid * 64 + l] = f;
}

// ---------------- Kernel 1: pre (MFMA) ----------------------------------
// sel=0: A rows (row layout).  sel=1: Bc in MFMA B-fragment layout.
__global__ __launch_bounds__(64) void pre_kernel(
    const float* __restrict__ h, const half8v* __restrict__ frags,
    _Float16* __restrict__ Ah, half8v* __restrict__ Bcf,
    half4v* __restrict__ Bcft)
{
    __shared__ _Float16 T[16][88];
    const int l = threadIdx.x, c16 = l & 15, g = l >> 4;
    const int sel = blockIdx.x & 1;
    const int m0 = (blockIdx.x >> 1) * 16;

    const float* hrow = h + (m0 + c16) * C_;
    half8v a0 = cvt8(hrow + g * 8);
    half8v a1 = cvt8(hrow + 32 + g * 8);
    half8v a2 = {};
    if (g == 0) a2 = cvt8(hrow + 64);
    else if (g == 1) a2[0] = (_Float16)1.0f;   // bias row k=72

    const half8v* F = frags + (sel ? FRAG_WE1B : FRAG_WE1A);
    f32x4 acc[5] = {};
    #pragma unroll
    for (int kt = 0; kt < 3; ++kt) {
        half8v a = (kt == 0) ? a0 : (kt == 1 ? a1 : a2);
        #pragma unroll
        for (int nt = 0; nt < 5; ++nt)
            acc[nt] = __builtin_amdgcn_mfma_f32_16x16x32_f16(a, F[(kt * 5 + nt) * 64 + l], acc[nt], 0, 0, 0);
    }

    if (sel == 0) {
        #pragma unroll
        for (int nt = 0; nt < 5; ++nt) {
            int n = nt * 16 + c16;
            if (n < C_) {
                #pragma unroll
                for (int r = 0; r < 4; ++r)
                    Ah[(m0 + 4 * g + r) * PADC + n] = (_Float16)acc[nt][r];
            }
        }
    } else {
        // D layout -> LDS -> B-fragment layout
        #pragma unroll
        for (int nt = 0; nt < 5; ++nt) {
            int n = nt * 16 + c16;
            if (n < C_) {
                #pragma unroll
                for (int r = 0; r < 4; ++r)
                    T[4 * g + r][n] = (_Float16)acc[nt][r];
            }
        }
        {   // zero pad cols 72..87
            int zr = l >> 2, zc = 72 + (l & 3) * 4;
            half4v z = {};
            *(half4v*)&T[zr][zc] = z;
        }
        __syncthreads();
        const int bb = m0 >> 7, jt = (m0 >> 4) & 7;
        half8v f0 = *(const half8v*)&T[c16][g * 8];
        half8v f1 = *(const half8v*)&T[c16][32 + g * 8];
        half4v ft = *(const half4v*)&T[c16][64 + g * 4];
        Bcf[((bb * 8 + jt) * 2 + 0) * 64 + l] = f0;
        Bcf[((bb * 8 + jt) * 2 + 1) * 64 + l] = f1;
        Bcft[(bb * 8 + jt) * 64 + l] = ft;
    }
}

// ---------------- Kernel 2: edge MLP — zero-LDS inner loop --------------
__global__ __launch_bounds__(256, 2) void edge_kernel(
    const float* __restrict__ x, const _Float16* __restrict__ Ah,
    const half8v* __restrict__ Bcf, const half4v* __restrict__ Bcft,
    const float* __restrict__ We1, const half8v* __restrict__ frags,
    const float* __restrict__ Wm, const float* __restrict__ bm,
    const float* __restrict__ Wx,
    float* __restrict__ wm_out, float* __restrict__ xacc_out)
{
    const int b  = blockIdx.x >> 5;
    const int it = blockIdx.x & 31;
    const int t  = threadIdx.x;
    const int wv = t >> 6;
    const int l  = t & 63;
    const int c16 = l & 15;
    const int g   = l >> 4;

    // ---- We2 fragments: 2x K32 + 1x K16 tail ----
    half8v Wf[2][5];
    #pragma unroll
    for (int kt = 0; kt < 2; ++kt)
        #pragma unroll
        for (int nt = 0; nt < 5; ++nt)
            Wf[kt][nt] = frags[FRAG_WE2 + (kt * 5 + nt) * 64 + l];
    half4v Wf2[5];
    {
        const half4v* tail = (const half4v*)(frags + NFRAG * 64);
        #pragma unroll
        for (int nt = 0; nt < 5; ++nt)
            Wf2[nt] = tail[nt * 64 + l];
    }

    // per-lane channel weights (ch = nt*16 + 4g + r)
    f32x2 WmWx[5][4];
    #pragma unroll
    for (int nt = 0; nt < 5; ++nt)
        #pragma unroll
        for (int r = 0; r < 4; ++r) {
            int ch = nt * 16 + 4 * g + r;
            bool ok = ch < C_;
            WmWx[nt][r][0] = ok ? Wm[ch] : 0.f;
            WmWx[nt][r][1] = ok ? Wx[ch] : 0.f;
        }
    const float bm0 = bm[0];
    const f32x4 zero4 = {0.f, 0.f, 0.f, 0.f};

    // ---- wave-lifetime register constants ----
    const float* w1g = We1 + 144 * C_;
    const float* w2g = We1 + 145 * C_;
    half8v w1a = cvt8(w1g + g * 8);
    half8v w1b = cvt8(w1g + 32 + g * 8);
    half8v w2a = cvt8(w2g + g * 8);
    half8v w2b = cvt8(w2g + 32 + g * 8);
    half4v w1t = {}, w2t = {};
    if (g < 2) { w1t = cvt4(w1g + 64 + g * 4); w2t = cvt4(w2g + 64 + g * 4); }

    const int i = it * IT + wv;            // wave owns one i-row
    const int node_i = b * P_ + i;
    const f32x4 xi = *(const f32x4*)&x[node_i * 4];
    const _Float16* Arow = Ah + node_i * PADC;
    half8v a0 = *(const half8v*)&Arow[g * 8];
    half8v a1 = *(const half8v*)&Arow[32 + g * 8];
    half4v at = {};
    if (g < 2) at = *(const half4v*)&Arow[64 + g * 4];

    const half8v* Bb = Bcf + (size_t)(b * 8) * 2 * 64;
    const half4v* Bt = Bcft + (size_t)(b * 8) * 64;
    const float*  xb = x + b * P_ * 4;

    // prefetch tile 0
    half8v bc0 = Bb[l];
    half8v bc1 = Bb[64 + l];
    half4v bct = Bt[l];
    f32x4 xjv = *(const f32x4*)&xb[c16 * 4];

    f32x4 wmacc[5] = {};
    f32x4 xacc = {0.f, 0.f, 0.f, 0.f};

    #pragma unroll 1
    for (int jt = 0; jt < 8; ++jt) {
        // ---- issue prefetch for next tile (wraps harmlessly) ----
        const int njt = (jt + 1) & 7;
        half8v nbc0 = Bb[(njt * 2) * 64 + l];
        half8v nbc1 = Bb[(njt * 2 + 1) * 64 + l];
        half4v nbct = Bt[njt * 64 + l];
        f32x4 nxjv = *(const f32x4*)&xb[(njt * 16 + c16) * 4];

        // ---- phase A: geometry + m1^T fragment in registers ----
        float d0 = xi[0] - xjv[0], d1 = xi[1] - xjv[1];
        float d2 = xi[2] - xjv[2], d3 = xi[3] - xjv[3];
        float nn = d0 * d0 - d1 * d1 - d2 * d2 - d3 * d3;
        float pp = xi[0] * xjv[0] - xi[1] * xjv[1] - xi[2] * xjv[2] - xi[3] * xjv[3];
        _Float16 nh = (_Float16)psi_f(nn);
        _Float16 ph = (_Float16)psi_f(pp);
        half8v n8 = {nh, nh, nh, nh, nh, nh, nh, nh};
        half8v p8 = {ph, ph, ph, ph, ph, ph, ph, ph};
        half8v zero8 = {};

        half8v af0, af1;
        {
            half8v v = a0 + bc0;
            v = __builtin_elementwise_fma(w1a, n8, v);
            v = __builtin_elementwise_fma(w2a, p8, v);
            af0 = __builtin_elementwise_max(v, zero8);
            half8v u = a1 + bc1;
            u = __builtin_elementwise_fma(w1b, n8, u);
            u = __builtin_elementwise_fma(w2b, p8, u);
            af1 = __builtin_elementwise_max(u, zero8);
        }
        half4v af2 = {};
        if (g < 2) {
            half4v n4 = {nh, nh, nh, nh};
            half4v p4 = {ph, ph, ph, ph};
            half4v zero4h = {};
            half4v v = at + bct;
            v = __builtin_elementwise_fma(w1t, n4, v);
            v = __builtin_elementwise_fma(w2t, p4, v);
            af2 = __builtin_elementwise_max(v, zero4h);
        } else if (g == 2) {
            af2[0] = (_Float16)1.0f;   // be2 bias row k=72
        }

        // ---- phase B: D[ch][edge] = We2^T @ m1^T (2x K32 + 1x K16) ----
        f32x4 acc[5] = {};
        #pragma unroll
        for (int nt = 0; nt < 5; ++nt)
            acc[nt] = __builtin_amdgcn_mfma_f32_16x16x32_f16(Wf[0][nt], af0, acc[nt], 0, 0, 0);
        #pragma unroll
        for (int nt = 0; nt < 5; ++nt)
            acc[nt] = __builtin_amdgcn_mfma_f32_16x16x32_f16(Wf[1][nt], af1, acc[nt], 0, 0, 0);
        #pragma unroll
        for (int nt = 0; nt < 5; ++nt)
            acc[nt] = __builtin_amdgcn_mfma_f32_16x16x16f16(Wf2[nt], af2, acc[nt], 0, 0, 0);

        // ---- phase C: lane owns edge j; packed f32x2 dots ----
        f32x2 wdpd = {0.f, 0.f};
        #pragma unroll
        for (int nt = 0; nt < 5; ++nt) {
            f32x4 m2q = __builtin_elementwise_max(acc[nt], zero4);
            acc[nt] = m2q;
            #pragma unroll
            for (int r = 0; r < 4; ++r) {
                f32x2 vv = {m2q[r], m2q[r]};
                wdpd = __builtin_elementwise_fma(vv, WmWx[nt][r], wdpd);
            }
        }
        // reduce across the 4 g-groups (lanes xor 16, 32)
        {
            f32x2 s;
            s[0] = __shfl_xor(wdpd[0], 16, 64);
            s[1] = __shfl_xor(wdpd[1], 16, 64);
            wdpd += s;
            s[0] = __shfl_xor(wdpd[0], 32, 64);
            s[1] = __shfl_xor(wdpd[1], 32, 64);
            wdpd += s;
        }
        float w_ = __builtin_amdgcn_rcpf(1.f + __expf(-(wdpd[0] + bm0)));
        f32x4 w4 = {w_, w_, w_, w_};
        #pragma unroll
        for (int nt = 0; nt < 5; ++nt)
            wmacc[nt] = __builtin_elementwise_fma(w4, acc[nt], wmacc[nt]);
        f32x4 pd4 = {wdpd[1], wdpd[1], wdpd[1], wdpd[1]};
        xacc = __builtin_elementwise_fma(pd4, xjv, xacc);

        bc0 = nbc0; bc1 = nbc1; bct = nbct; xjv = nxjv;
    } // jt

    // ---- finalize: sum across the 16 edge-lanes of each row ----
    #pragma unroll
    for (int nt = 0; nt < 5; ++nt)
        #pragma unroll
        for (int r = 0; r < 4; ++r)
            wmacc[nt][r] = red16(wmacc[nt][r]);
    #pragma unroll
    for (int q = 0; q < 4; ++q) xacc[q] = red16(xacc[q]);

    if (c16 == 0) {
        #pragma unroll
        for (int nt = 0; nt < 5; ++nt)
            #pragma unroll
            for (int r = 0; r < 4; ++r) {
                int ch = nt * 16 + 4 * g + r;
                if (ch < C_) wm_out[node_i * C_ + ch] = wmacc[nt][r];
            }
    }
    if (l == 0)
        *(f32x4*)&xacc_out[node_i * 4] = xacc;
}

// ---------------- Kernel 3: node MLP (chained MFMAs, frag loads) --------
__global__ __launch_bounds__(64) void node_kernel(
    const float* __restrict__ x, const float* __restrict__ h,
    const half8v* __restrict__ frags,
    const float* __restrict__ wm, const float* __restrict__ xacc,
    float* __restrict__ hout, float* __restrict__ xout)
{
    __shared__ _Float16 g_s[16][88];
    const int l = threadIdx.x, c16 = l & 15, g = l >> 4;
    const int m0 = blockIdx.x * 16;

    const float* hrow  = h  + (m0 + c16) * C_;
    const float* wmrow = wm + (m0 + c16) * C_;

    // ---- GEMM1: [h|wm|1] (K=160) @ Wh1(+bh1 row 144) ----
    half8v a[5];
    #pragma unroll
    for (int kt = 0; kt < 5; ++kt) {
        int k = kt * 32 + g * 8;
        half8v v = {};
        if (k < C_) v = cvt8(hrow + k);
        else if (k < 144) v = cvt8(wmrow + (k - C_));
        else if (k == 144) v[0] = (_Float16)1.0f;
        a[kt] = v;
    }
    f32x4 acc1[5] = {};
    #pragma unroll
    for (int kt = 0; kt < 5; ++kt)
        #pragma unroll
        for (int nt = 0; nt < 5; ++nt)
            acc1[nt] = __builtin_amdgcn_mfma_f32_16x16x32_f16(
                a[kt], frags[FRAG_WH1 + (kt * 5 + nt) * 64 + l], acc1[nt], 0, 0, 0);

    // relu -> wave-local LDS transpose (D layout -> A-fragment layout)
    #pragma unroll
    for (int nt = 0; nt < 5; ++nt) {
        int n = nt * 16 + c16;
        #pragma unroll
        for (int r = 0; r < 4; ++r)
            g_s[4 * g + r][n] = (_Float16)fmaxf(acc1[nt][r], 0.f);
    }
    __syncthreads();
    half8v b0 = *(const half8v*)&g_s[c16][g * 8];
    half8v b1 = *(const half8v*)&g_s[c16][32 + g * 8];
    half8v b2 = {};
    if (g == 0) b2 = *(const half8v*)&g_s[c16][64];
    else if (g == 1) b2[0] = (_Float16)1.0f;   // bh2 bias row k=72

    // ---- GEMM2: g (K=96) @ Wh2(+bh2 row 72) ----
    f32x4 acc2[5] = {};
    #pragma unroll
    for (int kt = 0; kt < 3; ++kt) {
        half8v aa = (kt == 0) ? b0 : (kt == 1 ? b1 : b2);
        #pragma unroll
        for (int nt = 0; nt < 5; ++nt)
            acc2[nt] = __builtin_amdgcn_mfma_f32_16x16x32_f16(
                aa, frags[FRAG_WH2 + (kt * 5 + nt) * 64 + l], acc2[nt], 0, 0, 0);
    }
    #pragma unroll
    for (int nt = 0; nt < 5; ++nt) {
        int n = nt * 16 + c16;
        if (n < C_) {
            #pragma unroll
            for (int r = 0; r < 4; ++r) {
                int row = m0 + 4 * g + r;
                hout[row * C_ + n] = h[row * C_ + n] + acc2[nt][r];
            }
        }
    }
    {
        int row = m0 + (l >> 2), d = l & 3;
        xout[row * 4 + d] = x[row * 4 + d] + 0.005f * (xacc[row * 4 + d] * (1.0f / 128.f));
    }
}

extern "C" void kernel_launch(void* const* d_in, const int* in_sizes, int n_in,
                              void* d_out, int out_size, void* d_ws, size_t ws_size,
                              hipStream_t stream) {
    const float* x   = (const float*)d_in[0];
    const float* h   = (const float*)d_in[1];
    const float* We1 = (const float*)d_in[2];
    const float* be1 = (const float*)d_in[3];
    const float* We2 = (const float*)d_in[4];
    const float* be2 = (const float*)d_in[5];
    const float* Wm  = (const float*)d_in[6];
    const float* bm  = (const float*)d_in[7];
    const float* Wh1 = (const float*)d_in[8];
    const float* bh1 = (const float*)d_in[9];
    const float* Wh2 = (const float*)d_in[10];
    const float* bh2 = (const float*)d_in[11];
    const float* Wx  = (const float*)d_in[12];

    const int NNODE = B_ * P_;                        // 8192
    _Float16* Ah  = (_Float16*)d_ws;                  // [8192][80] f16
    half8v* Bcf   = (half8v*)(Ah + NNODE * PADC);     // 64*8*2*64 half8v = 1 MB
    half4v* Bcft  = (half4v*)(Bcf + B_ * 8 * 2 * 64); // 64*8*64 half4v = 256 KB
    float* wm     = (float*)(Bcft + B_ * 8 * 64);     // [8192][72] f32
    float* xacc   = wm + NNODE * C_;                  // [8192][4]  f32
    half8v* frags = (half8v*)(xacc + NNODE * 4);      // 85 frags + 5 tail

    float* hout = (float*)d_out;                      // [8192][72]
    float* xout = hout + NNODE * C_;                  // [8192][4]

    setup_kernel<<<NFRAG + 5, 64, 0, stream>>>(We1, be1, We2, be2, Wh1, bh1, Wh2, bh2, frags);
    pre_kernel<<<NNODE / 16 * 2, 64, 0, stream>>>(h, frags, Ah, Bcf, Bcft);
    edge_kernel<<<B_ * 32, 256, 0, stream>>>(x, Ah, Bcf, Bcft, We1, frags,
                                             Wm, bm, Wx, wm, xacc);
    node_kernel<<<NNODE / 16, 64, 0, stream>>>(x, h, frags, wm, xacc, hout, xout);
}

// Round 13
// 59.866 us; speedup vs baseline: 4.4575x; 1.0073x over previous
//
#include <hip/hip_runtime.h>
#include <hip/hip_bf16.h>
#include <math.h>

#define B_ 64
#define P_ 128
#define C_ 72
#define PADC 80    // f16 global row stride for Ah
#define IT 4       // i-rows per edge block (1 per wave)

typedef __attribute__((ext_vector_type(8))) _Float16 half8v;
typedef __attribute__((ext_vector_type(4))) _Float16 half4v;
typedef __attribute__((ext_vector_type(4))) float f32x4;
typedef __attribute__((ext_vector_type(2))) float f32x2;

// precomputed weight-fragment table (units: half8v, 64 per fragment)
#define FRAG_WE2  0          // We2 kt=0,1 (K32), 15 frag slots
#define FRAG_WE1A (15 * 64)  // We1 rows 0..71, 15 frags
#define FRAG_WE1B (30 * 64)  // We1 rows 72..143 (+be1 @k=72), 15 frags
#define FRAG_WH1  (45 * 64)  // Wh1 (+bh1 @k=144), 25 frags
#define FRAG_WH2  (70 * 64)  // Wh2 (+bh2 @k=72), 15 frags
#define NFRAG 85             // + 5 K16-tail frags (half4v) appended

__device__ __forceinline__ float psi_f(float v) {
    float a = fabsf(v);
    return copysignf(__logf(1.0f + a), v);
}
template <int CTRL>
__device__ __forceinline__ float dpp_add(float v) {
    int s = __builtin_amdgcn_update_dpp(0, __builtin_bit_cast(int, v), CTRL, 0xF, 0xF, true);
    return v + __builtin_bit_cast(float, s);
}
// full sum across each 16-lane group (fixed tree -> deterministic)
__device__ __forceinline__ float red16(float v) {
    v = dpp_add<0xB1>(v);    // quad_perm(1,0,3,2)
    v = dpp_add<0x4E>(v);    // quad_perm(2,3,0,1)
    v = dpp_add<0x141>(v);   // row_half_mirror
    v = dpp_add<0x140>(v);   // row_mirror
    return v;
}
__device__ __forceinline__ half8v cvt8(const float* p) {
    f32x4 a = *(const f32x4*)p;
    f32x4 b = *(const f32x4*)(p + 4);
    half8v r = {(_Float16)a[0], (_Float16)a[1], (_Float16)a[2], (_Float16)a[3],
                (_Float16)b[0], (_Float16)b[1], (_Float16)b[2], (_Float16)b[3]};
    return r;
}
__device__ __forceinline__ half4v cvt4(const float* p) {
    f32x4 a = *(const f32x4*)p;
    half4v r = {(_Float16)a[0], (_Float16)a[1], (_Float16)a[2], (_Float16)a[3]};
    return r;
}

// ---------------- Kernel 0: build all weight fragments ------------------
__global__ __launch_bounds__(64) void setup_kernel(
    const float* __restrict__ We1, const float* __restrict__ be1,
    const float* __restrict__ We2, const float* __restrict__ be2,
    const float* __restrict__ Wh1, const float* __restrict__ bh1,
    const float* __restrict__ Wh2, const float* __restrict__ bh2,
    half8v* __restrict__ frags)
{
    const int bid = blockIdx.x;
    const int l = threadIdx.x;
    const int c16 = l & 15, g = l >> 4;

    if (bid >= NFRAG) {
        // K16 tail frags for edge We2: k = 64 + 4g + jj, bias(be2) at k=72
        half4v* tail = (half4v*)(frags + NFRAG * 64);
        const int nt = bid - NFRAG;
        const int n = nt * 16 + c16;
        half4v f = {};
        if (n < C_) {
            #pragma unroll
            for (int jj = 0; jj < 4; ++jj) {
                int k = 64 + 4 * g + jj;
                float w = 0.f;
                if (k < C_) w = We2[k * C_ + n];
                else if (k == C_) w = be2[n];
                f[jj] = (_Float16)w;
            }
        }
        tail[nt * 64 + l] = f;
        return;
    }

    const float* W;
    const float* bias;
    int kmax, rel;
    if (bid < 15)      { W = We2;            bias = be2;     kmax = 72;  rel = bid; }
    else if (bid < 30) { W = We1;            bias = nullptr; kmax = 72;  rel = bid - 15; }
    else if (bid < 45) { W = We1 + 72 * C_;  bias = be1;     kmax = 72;  rel = bid - 30; }
    else if (bid < 70) { W = Wh1;            bias = bh1;     kmax = 144; rel = bid - 45; }
    else               { W = Wh2;            bias = bh2;     kmax = 72;  rel = bid - 70; }
    const int kt = rel / 5, nt = rel - 5 * kt;
    const int n = nt * 16 + c16;

    half8v f = {};
    if (n < C_) {
        #pragma unroll
        for (int jj = 0; jj < 8; ++jj) {
            int k = kt * 32 + g * 8 + jj;
            float w = 0.f;
            if (k < kmax) w = W[k * C_ + n];
            else if (k == kmax && bias) w = bias[n];
            f[jj] = (_Float16)w;
        }
    }
    frags[bid * 64 + l] = f;
}

// ---------------- Kernel 1: pre (MFMA) ----------------------------------
// sel=0: A rows (row layout).  sel=1: Bc in MFMA B-fragment layout.
__global__ __launch_bounds__(64) void pre_kernel(
    const float* __restrict__ h, const half8v* __restrict__ frags,
    _Float16* __restrict__ Ah, half8v* __restrict__ Bcf,
    half4v* __restrict__ Bcft)
{
    __shared__ _Float16 T[16][88];
    const int l = threadIdx.x, c16 = l & 15, g = l >> 4;
    const int sel = blockIdx.x & 1;
    const int m0 = (blockIdx.x >> 1) * 16;

    const float* hrow = h + (m0 + c16) * C_;
    half8v a0 = cvt8(hrow + g * 8);
    half8v a1 = cvt8(hrow + 32 + g * 8);
    half8v a2 = {};
    if (g == 0) a2 = cvt8(hrow + 64);
    else if (g == 1) a2[0] = (_Float16)1.0f;   // bias row k=72

    const half8v* F = frags + (sel ? FRAG_WE1B : FRAG_WE1A);
    f32x4 acc[5] = {};
    #pragma unroll
    for (int kt = 0; kt < 3; ++kt) {
        half8v a = (kt == 0) ? a0 : (kt == 1 ? a1 : a2);
        #pragma unroll
        for (int nt = 0; nt < 5; ++nt)
            acc[nt] = __builtin_amdgcn_mfma_f32_16x16x32_f16(a, F[(kt * 5 + nt) * 64 + l], acc[nt], 0, 0, 0);
    }

    if (sel == 0) {
        #pragma unroll
        for (int nt = 0; nt < 5; ++nt) {
            int n = nt * 16 + c16;
            if (n < C_) {
                #pragma unroll
                for (int r = 0; r < 4; ++r)
                    Ah[(m0 + 4 * g + r) * PADC + n] = (_Float16)acc[nt][r];
            }
        }
    } else {
        // D layout -> LDS -> B-fragment layout
        #pragma unroll
        for (int nt = 0; nt < 5; ++nt) {
            int n = nt * 16 + c16;
            if (n < C_) {
                #pragma unroll
                for (int r = 0; r < 4; ++r)
                    T[4 * g + r][n] = (_Float16)acc[nt][r];
            }
        }
        {   // zero pad cols 72..87
            int zr = l >> 2, zc = 72 + (l & 3) * 4;
            half4v z = {};
            *(half4v*)&T[zr][zc] = z;
        }
        __syncthreads();
        const int bb = m0 >> 7, jt = (m0 >> 4) & 7;
        half8v f0 = *(const half8v*)&T[c16][g * 8];
        half8v f1 = *(const half8v*)&T[c16][32 + g * 8];
        half4v ft = *(const half4v*)&T[c16][64 + g * 4];
        Bcf[((bb * 8 + jt) * 2 + 0) * 64 + l] = f0;
        Bcf[((bb * 8 + jt) * 2 + 1) * 64 + l] = f1;
        Bcft[(bb * 8 + jt) * 64 + l] = ft;
    }
}

// ---------------- Kernel 2: edge MLP — zero-LDS, trans-pipelined --------
__global__ __launch_bounds__(256, 2) void edge_kernel(
    const float* __restrict__ x, const _Float16* __restrict__ Ah,
    const half8v* __restrict__ Bcf, const half4v* __restrict__ Bcft,
    const float* __restrict__ We1, const half8v* __restrict__ frags,
    const float* __restrict__ Wm, const float* __restrict__ bm,
    const float* __restrict__ Wx,
    float* __restrict__ wm_out, float* __restrict__ xacc_out)
{
    const int b  = blockIdx.x >> 5;
    const int it = blockIdx.x & 31;
    const int t  = threadIdx.x;
    const int wv = t >> 6;
    const int l  = t & 63;
    const int c16 = l & 15;
    const int g   = l >> 4;

    // ---- We2 fragments: 2x K32 + 1x K16 tail ----
    half8v Wf[2][5];
    #pragma unroll
    for (int kt = 0; kt < 2; ++kt)
        #pragma unroll
        for (int nt = 0; nt < 5; ++nt)
            Wf[kt][nt] = frags[FRAG_WE2 + (kt * 5 + nt) * 64 + l];
    half4v Wf2[5];
    {
        const half4v* tail = (const half4v*)(frags + NFRAG * 64);
        #pragma unroll
        for (int nt = 0; nt < 5; ++nt)
            Wf2[nt] = tail[nt * 64 + l];
    }

    // per-lane channel weights (ch = nt*16 + 4g + r)
    f32x2 WmWx[5][4];
    #pragma unroll
    for (int nt = 0; nt < 5; ++nt)
        #pragma unroll
        for (int r = 0; r < 4; ++r) {
            int ch = nt * 16 + 4 * g + r;
            bool ok = ch < C_;
            WmWx[nt][r][0] = ok ? Wm[ch] : 0.f;
            WmWx[nt][r][1] = ok ? Wx[ch] : 0.f;
        }
    const float bm0 = bm[0];
    const f32x4 zero4 = {0.f, 0.f, 0.f, 0.f};

    // ---- wave-lifetime register constants ----
    const float* w1g = We1 + 144 * C_;
    const float* w2g = We1 + 145 * C_;
    half8v w1a = cvt8(w1g + g * 8);
    half8v w1b = cvt8(w1g + 32 + g * 8);
    half8v w2a = cvt8(w2g + g * 8);
    half8v w2b = cvt8(w2g + 32 + g * 8);
    half4v w1t = {}, w2t = {};
    if (g < 2) { w1t = cvt4(w1g + 64 + g * 4); w2t = cvt4(w2g + 64 + g * 4); }

    const int i = it * IT + wv;            // wave owns one i-row
    const int node_i = b * P_ + i;
    const f32x4 xi = *(const f32x4*)&x[node_i * 4];
    const _Float16* Arow = Ah + node_i * PADC;
    half8v a0 = *(const half8v*)&Arow[g * 8];
    half8v a1 = *(const half8v*)&Arow[32 + g * 8];
    half4v at = {};
    if (g < 2) at = *(const half4v*)&Arow[64 + g * 4];

    const half8v* Bb = Bcf + (size_t)(b * 8) * 2 * 64;
    const half4v* Bt = Bcft + (size_t)(b * 8) * 64;
    const float*  xb = x + b * P_ * 4;

    // ---- pipeline preload: Bc 1-deep, xj 2-deep, geom(0) precomputed ----
    half8v bc0 = Bb[l];
    half8v bc1 = Bb[64 + l];
    half4v bct = Bt[l];
    f32x4 xjv_c = *(const f32x4*)&xb[c16 * 4];           // xj(0)
    f32x4 xjv_n = *(const f32x4*)&xb[(16 + c16) * 4];    // xj(1)
    _Float16 nh_c, ph_c;
    {
        float d0 = xi[0] - xjv_c[0], d1 = xi[1] - xjv_c[1];
        float d2 = xi[2] - xjv_c[2], d3 = xi[3] - xjv_c[3];
        float nn = d0 * d0 - d1 * d1 - d2 * d2 - d3 * d3;
        float pp = xi[0] * xjv_c[0] - xi[1] * xjv_c[1] - xi[2] * xjv_c[2] - xi[3] * xjv_c[3];
        nh_c = (_Float16)psi_f(nn);
        ph_c = (_Float16)psi_f(pp);
    }

    f32x4 wmacc[5] = {};
    f32x4 xacc = {0.f, 0.f, 0.f, 0.f};

    #pragma unroll 1
    for (int jt = 0; jt < 8; ++jt) {
        // ---- issue next-tile loads (Bc t+1, xj t+2; wrap harmless) ----
        const int njt = (jt + 1) & 7;
        const int fjt = (jt + 2) & 7;
        half8v nbc0 = Bb[(njt * 2) * 64 + l];
        half8v nbc1 = Bb[(njt * 2 + 1) * 64 + l];
        half4v nbct = Bt[njt * 64 + l];
        f32x4 xjv_f = *(const f32x4*)&xb[(fjt * 16 + c16) * 4];

        // ---- phase A: m1^T fragment for tile jt (psi already done) ----
        half8v n8 = {nh_c, nh_c, nh_c, nh_c, nh_c, nh_c, nh_c, nh_c};
        half8v p8 = {ph_c, ph_c, ph_c, ph_c, ph_c, ph_c, ph_c, ph_c};
        half8v zero8 = {};

        half8v af0, af1;
        {
            half8v v = a0 + bc0;
            v = __builtin_elementwise_fma(w1a, n8, v);
            v = __builtin_elementwise_fma(w2a, p8, v);
            af0 = __builtin_elementwise_max(v, zero8);
            half8v u = a1 + bc1;
            u = __builtin_elementwise_fma(w1b, n8, u);
            u = __builtin_elementwise_fma(w2b, p8, u);
            af1 = __builtin_elementwise_max(u, zero8);
        }
        half4v af2 = {};
        if (g < 2) {
            half4v n4 = {nh_c, nh_c, nh_c, nh_c};
            half4v p4 = {ph_c, ph_c, ph_c, ph_c};
            half4v zero4h = {};
            half4v v = at + bct;
            v = __builtin_elementwise_fma(w1t, n4, v);
            v = __builtin_elementwise_fma(w2t, p4, v);
            af2 = __builtin_elementwise_max(v, zero4h);
        } else if (g == 2) {
            af2[0] = (_Float16)1.0f;   // be2 bias row k=72
        }

        // ---- phase B: D[ch][edge] = We2^T @ m1^T (2x K32 + 1x K16) ----
        f32x4 acc[5] = {};
        #pragma unroll
        for (int nt = 0; nt < 5; ++nt)
            acc[nt] = __builtin_amdgcn_mfma_f32_16x16x32_f16(Wf[0][nt], af0, acc[nt], 0, 0, 0);
        #pragma unroll
        for (int nt = 0; nt < 5; ++nt)
            acc[nt] = __builtin_amdgcn_mfma_f32_16x16x32_f16(Wf[1][nt], af1, acc[nt], 0, 0, 0);
        #pragma unroll
        for (int nt = 0; nt < 5; ++nt)
            acc[nt] = __builtin_amdgcn_mfma_f32_16x16x16f16(Wf2[nt], af2, acc[nt], 0, 0, 0);

        // ---- overlapped: geometry + psi for tile jt+1 (hides under MFMA) ----
        _Float16 nh_n, ph_n;
        {
            float d0 = xi[0] - xjv_n[0], d1 = xi[1] - xjv_n[1];
            float d2 = xi[2] - xjv_n[2], d3 = xi[3] - xjv_n[3];
            float nn = d0 * d0 - d1 * d1 - d2 * d2 - d3 * d3;
            float pp = xi[0] * xjv_n[0] - xi[1] * xjv_n[1] - xi[2] * xjv_n[2] - xi[3] * xjv_n[3];
            nh_n = (_Float16)psi_f(nn);
            ph_n = (_Float16)psi_f(pp);
        }

        // ---- phase C: lane owns edge j; two independent dot chains ----
        f32x2 wdA = {0.f, 0.f}, wdB = {0.f, 0.f};
        #pragma unroll
        for (int nt = 0; nt < 5; ++nt) {
            f32x4 m2q = __builtin_elementwise_max(acc[nt], zero4);
            acc[nt] = m2q;
            f32x2 v0 = {m2q[0], m2q[0]};
            f32x2 v1 = {m2q[1], m2q[1]};
            f32x2 v2 = {m2q[2], m2q[2]};
            f32x2 v3 = {m2q[3], m2q[3]};
            wdA = __builtin_elementwise_fma(v0, WmWx[nt][0], wdA);
            wdB = __builtin_elementwise_fma(v1, WmWx[nt][1], wdB);
            wdA = __builtin_elementwise_fma(v2, WmWx[nt][2], wdA);
            wdB = __builtin_elementwise_fma(v3, WmWx[nt][3], wdB);
        }
        f32x2 wdpd = wdA + wdB;
        // reduce across the 4 g-groups (lanes xor 16, 32)
        {
            f32x2 s;
            s[0] = __shfl_xor(wdpd[0], 16, 64);
            s[1] = __shfl_xor(wdpd[1], 16, 64);
            wdpd += s;
            s[0] = __shfl_xor(wdpd[0], 32, 64);
            s[1] = __shfl_xor(wdpd[1], 32, 64);
            wdpd += s;
        }
        float w_ = __builtin_amdgcn_rcpf(1.f + __expf(-(wdpd[0] + bm0)));
        f32x4 w4 = {w_, w_, w_, w_};
        #pragma unroll
        for (int nt = 0; nt < 5; ++nt)
            wmacc[nt] = __builtin_elementwise_fma(w4, acc[nt], wmacc[nt]);
        f32x4 pd4 = {wdpd[1], wdpd[1], wdpd[1], wdpd[1]};
        xacc = __builtin_elementwise_fma(pd4, xjv_c, xacc);

        // ---- rotate pipeline registers ----
        bc0 = nbc0; bc1 = nbc1; bct = nbct;
        xjv_c = xjv_n; xjv_n = xjv_f;
        nh_c = nh_n; ph_c = ph_n;
    } // jt

    // ---- finalize: sum across the 16 edge-lanes of each row ----
    #pragma unroll
    for (int nt = 0; nt < 5; ++nt)
        #pragma unroll
        for (int r = 0; r < 4; ++r)
            wmacc[nt][r] = red16(wmacc[nt][r]);
    #pragma unroll
    for (int q = 0; q < 4; ++q) xacc[q] = red16(xacc[q]);

    if (c16 == 0) {
        #pragma unroll
        for (int nt = 0; nt < 5; ++nt)
            #pragma unroll
            for (int r = 0; r < 4; ++r) {
                int ch = nt * 16 + 4 * g + r;
                if (ch < C_) wm_out[node_i * C_ + ch] = wmacc[nt][r];
            }
    }
    if (l == 0)
        *(f32x4*)&xacc_out[node_i * 4] = xacc;
}

// ---------------- Kernel 3: node MLP (chained MFMAs, frag loads) --------
__global__ __launch_bounds__(64) void node_kernel(
    const float* __restrict__ x, const float* __restrict__ h,
    const half8v* __restrict__ frags,
    const float* __restrict__ wm, const float* __restrict__ xacc,
    float* __restrict__ hout, float* __restrict__ xout)
{
    __shared__ _Float16 g_s[16][88];
    const int l = threadIdx.x, c16 = l & 15, g = l >> 4;
    const int m0 = blockIdx.x * 16;

    const float* hrow  = h  + (m0 + c16) * C_;
    const float* wmrow = wm + (m0 + c16) * C_;

    // ---- GEMM1: [h|wm|1] (K=160) @ Wh1(+bh1 row 144) ----
    half8v a[5];
    #pragma unroll
    for (int kt = 0; kt < 5; ++kt) {
        int k = kt * 32 + g * 8;
        half8v v = {};
        if (k < C_) v = cvt8(hrow + k);
        else if (k < 144) v = cvt8(wmrow + (k - C_));
        else if (k == 144) v[0] = (_Float16)1.0f;
        a[kt] = v;
    }
    f32x4 acc1[5] = {};
    #pragma unroll
    for (int kt = 0; kt < 5; ++kt)
        #pragma unroll
        for (int nt = 0; nt < 5; ++nt)
            acc1[nt] = __builtin_amdgcn_mfma_f32_16x16x32_f16(
                a[kt], frags[FRAG_WH1 + (kt * 5 + nt) * 64 + l], acc1[nt], 0, 0, 0);

    // relu -> wave-local LDS transpose (D layout -> A-fragment layout)
    #pragma unroll
    for (int nt = 0; nt < 5; ++nt) {
        int n = nt * 16 + c16;
        #pragma unroll
        for (int r = 0; r < 4; ++r)
            g_s[4 * g + r][n] = (_Float16)fmaxf(acc1[nt][r], 0.f);
    }
    __syncthreads();
    half8v b0 = *(const half8v*)&g_s[c16][g * 8];
    half8v b1 = *(const half8v*)&g_s[c16][32 + g * 8];
    half8v b2 = {};
    if (g == 0) b2 = *(const half8v*)&g_s[c16][64];
    else if (g == 1) b2[0] = (_Float16)1.0f;   // bh2 bias row k=72

    // ---- GEMM2: g (K=96) @ Wh2(+bh2 row 72) ----
    f32x4 acc2[5] = {};
    #pragma unroll
    for (int kt = 0; kt < 3; ++kt) {
        half8v aa = (kt == 0) ? b0 : (kt == 1 ? b1 : b2);
        #pragma unroll
        for (int nt = 0; nt < 5; ++nt)
            acc2[nt] = __builtin_amdgcn_mfma_f32_16x16x32_f16(
                aa, frags[FRAG_WH2 + (kt * 5 + nt) * 64 + l], acc2[nt], 0, 0, 0);
    }
    #pragma unroll
    for (int nt = 0; nt < 5; ++nt) {
        int n = nt * 16 + c16;
        if (n < C_) {
            #pragma unroll
            for (int r = 0; r < 4; ++r) {
                int row = m0 + 4 * g + r;
                hout[row * C_ + n] = h[row * C_ + n] + acc2[nt][r];
            }
        }
    }
    {
        int row = m0 + (l >> 2), d = l & 3;
        xout[row * 4 + d] = x[row * 4 + d] + 0.005f * (xacc[row * 4 + d] * (1.0f / 128.f));
    }
}

extern "C" void kernel_launch(void* const* d_in, const int* in_sizes, int n_in,
                              void* d_out, int out_size, void* d_ws, size_t ws_size,
                              hipStream_t stream) {
    const float* x   = (const float*)d_in[0];
    const float* h   = (const float*)d_in[1];
    const float* We1 = (const float*)d_in[2];
    const float* be1 = (const float*)d_in[3];
    const float* We2 = (const float*)d_in[4];
    const float* be2 = (const float*)d_in[5];
    const float* Wm  = (const float*)d_in[6];
    const float* bm  = (const float*)d_in[7];
    const float* Wh1 = (const float*)d_in[8];
    const float* bh1 = (const float*)d_in[9];
    const float* Wh2 = (const float*)d_in[10];
    const float* bh2 = (const float*)d_in[11];
    const float* Wx  = (const float*)d_in[12];

    const int NNODE = B_ * P_;                        // 8192
    _Float16* Ah  = (_Float16*)d_ws;                  // [8192][80] f16
    half8v* Bcf   = (half8v*)(Ah + NNODE * PADC);     // 64*8*2*64 half8v = 1 MB
    half4v* Bcft  = (half4v*)(Bcf + B_ * 8 * 2 * 64); // 64*8*64 half4v = 256 KB
    float* wm     = (float*)(Bcft + B_ * 8 * 64);     // [8192][72] f32
    float* xacc   = wm + NNODE * C_;                  // [8192][4]  f32
    half8v* frags = (half8v*)(xacc + NNODE * 4);      // 85 frags + 5 tail

    float* hout = (float*)d_out;                      // [8192][72]
    float* xout = hout + NNODE * C_;                  // [8192][4]

    setup_kernel<<<NFRAG + 5, 64, 0, stream>>>(We1, be1, We2, be2, Wh1, bh1, Wh2, bh2, frags);
    pre_kernel<<<NNODE / 16 * 2, 64, 0, stream>>>(h, frags, Ah, Bcf, Bcft);
    edge_kernel<<<B_ * 32, 256, 0, stream>>>(x, Ah, Bcf, Bcft, We1, frags,
                                             Wm, bm, Wx, wm, xacc);
    node_kernel<<<NNODE / 16, 64, 0, stream>>>(x, h, frags, wm, xacc, hout, xout);
}

// Round 14
// 57.237 us; speedup vs baseline: 4.6622x; 1.0459x over previous
//
#include <hip/hip_runtime.h>
#include <hip/hip_bf16.h>
#include <math.h>

#define B_ 64
#define P_ 128
#define C_ 72
#define PADC 80    // f16 global row stride for Ah
#define IT 4       // i-rows per edge block (1 per wave)

typedef __attribute__((ext_vector_type(8))) _Float16 half8v;
typedef __attribute__((ext_vector_type(4))) _Float16 half4v;
typedef __attribute__((ext_vector_type(4))) float f32x4;
typedef __attribute__((ext_vector_type(2))) float f32x2;

// precomputed weight-fragment table (units: half8v, 64 per fragment)
#define FRAG_WE2  0          // We2 kt=0,1 (K32), 15 frag slots
#define FRAG_WE1A (15 * 64)  // We1 rows 0..71, 15 frags
#define FRAG_WE1B (30 * 64)  // We1 rows 72..143 (+be1 @k=72), 15 frags
#define FRAG_WH1  (45 * 64)  // Wh1 (+bh1 @k=144), 25 frags
#define FRAG_WH2  (70 * 64)  // Wh2 (+bh2 @k=72), 15 frags
#define NFRAG 85             // + 5 K16-tail frags (half4v) + w12p appended

__device__ __forceinline__ float psi_f(float v) {
    float a = fabsf(v);
    return copysignf(__logf(1.0f + a), v);
}
template <int CTRL>
__device__ __forceinline__ float dpp_add(float v) {
    int s = __builtin_amdgcn_update_dpp(0, __builtin_bit_cast(int, v), CTRL, 0xF, 0xF, true);
    return v + __builtin_bit_cast(float, s);
}
// full sum across each 16-lane group (fixed tree -> deterministic)
__device__ __forceinline__ float red16(float v) {
    v = dpp_add<0xB1>(v);    // quad_perm(1,0,3,2)
    v = dpp_add<0x4E>(v);    // quad_perm(2,3,0,1)
    v = dpp_add<0x141>(v);   // row_half_mirror
    v = dpp_add<0x140>(v);   // row_mirror
    return v;
}
__device__ __forceinline__ half8v cvt8(const float* p) {
    f32x4 a = *(const f32x4*)p;
    f32x4 b = *(const f32x4*)(p + 4);
    half8v r = {(_Float16)a[0], (_Float16)a[1], (_Float16)a[2], (_Float16)a[3],
                (_Float16)b[0], (_Float16)b[1], (_Float16)b[2], (_Float16)b[3]};
    return r;
}

// ---------------- Kernel 0: build all weight fragments ------------------
__global__ __launch_bounds__(64) void setup_kernel(
    const float* __restrict__ We1, const float* __restrict__ be1,
    const float* __restrict__ We2, const float* __restrict__ be2,
    const float* __restrict__ Wh1, const float* __restrict__ bh1,
    const float* __restrict__ Wh2, const float* __restrict__ bh2,
    half8v* __restrict__ frags)
{
    const int bid = blockIdx.x;
    const int l = threadIdx.x;
    const int c16 = l & 15, g = l >> 4;

    if (bid == NFRAG + 5) {
        // padded w144/w145 table: w12p[2][80], zeros beyond col 71
        _Float16* w12p = (_Float16*)((half4v*)(frags + NFRAG * 64) + 5 * 64);
        for (int i = l; i < 160; i += 64) {
            int s = i / 80, c = i - s * 80;
            w12p[i] = (c < C_) ? (_Float16)We1[(144 + s) * C_ + c] : (_Float16)0.f;
        }
        return;
    }
    if (bid >= NFRAG) {
        // K16 tail frags for edge We2: k = 64 + 4g + jj, bias(be2) at k=72
        half4v* tail = (half4v*)(frags + NFRAG * 64);
        const int nt = bid - NFRAG;
        const int n = nt * 16 + c16;
        half4v f = {};
        if (n < C_) {
            #pragma unroll
            for (int jj = 0; jj < 4; ++jj) {
                int k = 64 + 4 * g + jj;
                float w = 0.f;
                if (k < C_) w = We2[k * C_ + n];
                else if (k == C_) w = be2[n];
                f[jj] = (_Float16)w;
            }
        }
        tail[nt * 64 + l] = f;
        return;
    }

    const float* W;
    const float* bias;
    int kmax, rel;
    if (bid < 15)      { W = We2;            bias = be2;     kmax = 72;  rel = bid; }
    else if (bid < 30) { W = We1;            bias = nullptr; kmax = 72;  rel = bid - 15; }
    else if (bid < 45) { W = We1 + 72 * C_;  bias = be1;     kmax = 72;  rel = bid - 30; }
    else if (bid < 70) { W = Wh1;            bias = bh1;     kmax = 144; rel = bid - 45; }
    else               { W = Wh2;            bias = bh2;     kmax = 72;  rel = bid - 70; }
    const int kt = rel / 5, nt = rel - 5 * kt;
    const int n = nt * 16 + c16;

    half8v f = {};
    if (n < C_) {
        #pragma unroll
        for (int jj = 0; jj < 8; ++jj) {
            int k = kt * 32 + g * 8 + jj;
            float w = 0.f;
            if (k < kmax) w = W[k * C_ + n];
            else if (k == kmax && bias) w = bias[n];
            f[jj] = (_Float16)w;
        }
    }
    frags[bid * 64 + l] = f;
}

// ---------------- Kernel 1: pre (MFMA) ----------------------------------
// sel=0: A rows (row layout, bias 1.0 baked at col 72).  sel=1: Bc frags.
__global__ __launch_bounds__(64) void pre_kernel(
    const float* __restrict__ h, const half8v* __restrict__ frags,
    _Float16* __restrict__ Ah, half8v* __restrict__ Bcf,
    half4v* __restrict__ Bcft)
{
    __shared__ _Float16 T[16][88];
    const int l = threadIdx.x, c16 = l & 15, g = l >> 4;
    const int sel = blockIdx.x & 1;
    const int m0 = (blockIdx.x >> 1) * 16;

    const float* hrow = h + (m0 + c16) * C_;
    half8v a0 = cvt8(hrow + g * 8);
    half8v a1 = cvt8(hrow + 32 + g * 8);
    half8v a2 = {};
    if (g == 0) a2 = cvt8(hrow + 64);
    else if (g == 1) a2[0] = (_Float16)1.0f;   // bias row k=72

    const half8v* F = frags + (sel ? FRAG_WE1B : FRAG_WE1A);
    f32x4 acc[5] = {};
    #pragma unroll
    for (int kt = 0; kt < 3; ++kt) {
        half8v a = (kt == 0) ? a0 : (kt == 1 ? a1 : a2);
        #pragma unroll
        for (int nt = 0; nt < 5; ++nt)
            acc[nt] = __builtin_amdgcn_mfma_f32_16x16x32_f16(a, F[(kt * 5 + nt) * 64 + l], acc[nt], 0, 0, 0);
    }

    if (sel == 0) {
        #pragma unroll
        for (int nt = 0; nt < 5; ++nt) {
            int n = nt * 16 + c16;
            if (n < C_) {
                #pragma unroll
                for (int r = 0; r < 4; ++r)
                    Ah[(m0 + 4 * g + r) * PADC + n] = (_Float16)acc[nt][r];
            }
        }
        if (l < 16) {   // bake be2-bias marker: col 72 = 1.0, 73..79 = 0
            half4v one = {(_Float16)1.0f, (_Float16)0.f, (_Float16)0.f, (_Float16)0.f};
            half4v z = {};
            *(half4v*)&Ah[(m0 + l) * PADC + 72] = one;
            *(half4v*)&Ah[(m0 + l) * PADC + 76] = z;
        }
    } else {
        // D layout -> LDS -> B-fragment layout
        #pragma unroll
        for (int nt = 0; nt < 5; ++nt) {
            int n = nt * 16 + c16;
            if (n < C_) {
                #pragma unroll
                for (int r = 0; r < 4; ++r)
                    T[4 * g + r][n] = (_Float16)acc[nt][r];
            }
        }
        {   // zero pad cols 72..87
            int zr = l >> 2, zc = 72 + (l & 3) * 4;
            half4v z = {};
            *(half4v*)&T[zr][zc] = z;
        }
        __syncthreads();
        const int bb = m0 >> 7, jt = (m0 >> 4) & 7;
        half8v f0 = *(const half8v*)&T[c16][g * 8];
        half8v f1 = *(const half8v*)&T[c16][32 + g * 8];
        half4v ft = *(const half4v*)&T[c16][64 + g * 4];
        Bcf[((bb * 8 + jt) * 2 + 0) * 64 + l] = f0;
        Bcf[((bb * 8 + jt) * 2 + 1) * 64 + l] = f1;
        Bcft[(bb * 8 + jt) * 64 + l] = ft;
    }
}

// ---------------- Kernel 2: edge MLP — quad-dedup geometry --------------
__global__ __launch_bounds__(256, 2) void edge_kernel(
    const float* __restrict__ x, const _Float16* __restrict__ Ah,
    const half8v* __restrict__ Bcf, const half4v* __restrict__ Bcft,
    const half8v* __restrict__ frags,
    const float* __restrict__ Wm, const float* __restrict__ bm,
    const float* __restrict__ Wx,
    float* __restrict__ wm_out, float* __restrict__ xacc_out)
{
    const int b  = blockIdx.x >> 5;
    const int it = blockIdx.x & 31;
    const int t  = threadIdx.x;
    const int wv = t >> 6;
    const int l  = t & 63;
    const int c16 = l & 15;
    const int g   = l >> 4;

    // ---- We2 fragments: 2x K32 + 1x K16 tail ----
    half8v Wf[2][5];
    #pragma unroll
    for (int kt = 0; kt < 2; ++kt)
        #pragma unroll
        for (int nt = 0; nt < 5; ++nt)
            Wf[kt][nt] = frags[FRAG_WE2 + (kt * 5 + nt) * 64 + l];
    half4v Wf2[5];
    const half4v* tail = (const half4v*)(frags + NFRAG * 64);
    #pragma unroll
    for (int nt = 0; nt < 5; ++nt)
        Wf2[nt] = tail[nt * 64 + l];

    // padded w144/w145 table
    const _Float16* w12p = (const _Float16*)(tail + 5 * 64);
    half8v w1a = *(const half8v*)&w12p[g * 8];
    half8v w1b = *(const half8v*)&w12p[32 + g * 8];
    half4v w1t = *(const half4v*)&w12p[64 + g * 4];
    half8v w2a = *(const half8v*)&w12p[80 + g * 8];
    half8v w2b = *(const half8v*)&w12p[80 + 32 + g * 8];
    half4v w2t = *(const half4v*)&w12p[80 + 64 + g * 4];

    // per-lane channel weights (ch = nt*16 + 4g + r)
    f32x2 WmWx[5][4];
    #pragma unroll
    for (int nt = 0; nt < 5; ++nt)
        #pragma unroll
        for (int r = 0; r < 4; ++r) {
            int ch = nt * 16 + 4 * g + r;
            bool ok = ch < C_;
            WmWx[nt][r][0] = ok ? Wm[ch] : 0.f;
            WmWx[nt][r][1] = ok ? Wx[ch] : 0.f;
        }
    const float bm0 = bm[0];
    const f32x4 zero4 = {0.f, 0.f, 0.f, 0.f};

    const int i = it * IT + wv;            // wave owns one i-row
    const int node_i = b * P_ + i;
    const f32x4 xi = *(const f32x4*)&x[node_i * 4];
    const _Float16* Arow = Ah + node_i * PADC;
    half8v a0 = *(const half8v*)&Arow[g * 8];
    half8v a1 = *(const half8v*)&Arow[32 + g * 8];
    half4v at = *(const half4v*)&Arow[64 + g * 4];   // g=2 carries baked bias 1.0

    const half8v* Bb = Bcf + (size_t)(b * 8) * 2 * 64;
    const half4v* Bt = Bcft + (size_t)(b * 8) * 64;
    const float*  xb = x + b * P_ * 4;

    // Bc prefetch, 1-deep
    half8v bc0 = Bb[l];
    half8v bc1 = Bb[64 + l];
    half4v bct = Bt[l];

    f32x4 wmacc[5] = {};
    f32x4 xacc = {0.f, 0.f, 0.f, 0.f};
    const int c16_4 = c16 << 2;

    #pragma unroll 1
    for (int q = 0; q < 2; ++q) {
        // ---- 64-edge geometry + psi, computed ONCE per 4 tiles ----
        f32x4 xjq = *(const f32x4*)&xb[(q * 64 + l) * 4];
        float d0 = xi[0] - xjq[0], d1 = xi[1] - xjq[1];
        float d2 = xi[2] - xjq[2], d3 = xi[3] - xjq[3];
        float nn = d0 * d0 - d1 * d1 - d2 * d2 - d3 * d3;
        float pp = xi[0] * xjq[0] - xi[1] * xjq[1] - xi[2] * xjq[2] - xi[3] * xjq[3];
        unsigned geo =
            (unsigned)__builtin_bit_cast(unsigned short, (_Float16)psi_f(nn)) |
            ((unsigned)__builtin_bit_cast(unsigned short, (_Float16)psi_f(pp)) << 16);
        int geo0 = __builtin_amdgcn_ds_bpermute(c16_4,       (int)geo);
        int geo1 = __builtin_amdgcn_ds_bpermute(c16_4 + 64,  (int)geo);
        int geo2 = __builtin_amdgcn_ds_bpermute(c16_4 + 128, (int)geo);
        int geo3 = __builtin_amdgcn_ds_bpermute(c16_4 + 192, (int)geo);

        #pragma unroll
        for (int s = 0; s < 4; ++s) {
            const int jt = q * 4 + s;
            const int njt = (jt + 1) & 7;
            half8v nbc0 = Bb[(njt * 2) * 64 + l];
            half8v nbc1 = Bb[(njt * 2 + 1) * 64 + l];
            half4v nbct = Bt[njt * 64 + l];
            f32x4 xjv = *(const f32x4*)&xb[(jt * 16 + c16) * 4];

            int geos = (s == 0) ? geo0 : (s == 1) ? geo1 : (s == 2) ? geo2 : geo3;
            _Float16 nh = __builtin_bit_cast(_Float16, (unsigned short)((unsigned)geos & 0xFFFFu));
            _Float16 ph = __builtin_bit_cast(_Float16, (unsigned short)((unsigned)geos >> 16));
            half8v n8 = {nh, nh, nh, nh, nh, nh, nh, nh};
            half8v p8 = {ph, ph, ph, ph, ph, ph, ph, ph};
            half4v n4 = {nh, nh, nh, nh};
            half4v p4 = {ph, ph, ph, ph};
            half8v zero8 = {};
            half4v zero4h = {};

            // ---- phase A: m1^T fragments (branch-free tail) ----
            half8v v0 = a0 + bc0;
            v0 = __builtin_elementwise_fma(w1a, n8, v0);
            v0 = __builtin_elementwise_fma(w2a, p8, v0);
            half8v af0 = __builtin_elementwise_max(v0, zero8);
            half8v v1 = a1 + bc1;
            v1 = __builtin_elementwise_fma(w1b, n8, v1);
            v1 = __builtin_elementwise_fma(w2b, p8, v1);
            half8v af1 = __builtin_elementwise_max(v1, zero8);
            half4v vt = at + bct;
            vt = __builtin_elementwise_fma(w1t, n4, vt);
            vt = __builtin_elementwise_fma(w2t, p4, vt);
            half4v af2 = __builtin_elementwise_max(vt, zero4h);

            // ---- phase B: D[ch][edge] = We2^T @ m1^T ----
            f32x4 acc[5] = {};
            #pragma unroll
            for (int nt = 0; nt < 5; ++nt)
                acc[nt] = __builtin_amdgcn_mfma_f32_16x16x32_f16(Wf[0][nt], af0, acc[nt], 0, 0, 0);
            #pragma unroll
            for (int nt = 0; nt < 5; ++nt)
                acc[nt] = __builtin_amdgcn_mfma_f32_16x16x32_f16(Wf[1][nt], af1, acc[nt], 0, 0, 0);
            #pragma unroll
            for (int nt = 0; nt < 5; ++nt)
                acc[nt] = __builtin_amdgcn_mfma_f32_16x16x16f16(Wf2[nt], af2, acc[nt], 0, 0, 0);

            // ---- phase C: two independent dot chains ----
            f32x2 wdA = {0.f, 0.f}, wdB = {0.f, 0.f};
            #pragma unroll
            for (int nt = 0; nt < 5; ++nt) {
                f32x4 m2q = __builtin_elementwise_max(acc[nt], zero4);
                acc[nt] = m2q;
                f32x2 e0 = {m2q[0], m2q[0]};
                f32x2 e1 = {m2q[1], m2q[1]};
                f32x2 e2 = {m2q[2], m2q[2]};
                f32x2 e3 = {m2q[3], m2q[3]};
                wdA = __builtin_elementwise_fma(e0, WmWx[nt][0], wdA);
                wdB = __builtin_elementwise_fma(e1, WmWx[nt][1], wdB);
                wdA = __builtin_elementwise_fma(e2, WmWx[nt][2], wdA);
                wdB = __builtin_elementwise_fma(e3, WmWx[nt][3], wdB);
            }
            f32x2 wdpd = wdA + wdB;
            {
                f32x2 sx;
                sx[0] = __shfl_xor(wdpd[0], 16, 64);
                sx[1] = __shfl_xor(wdpd[1], 16, 64);
                wdpd += sx;
                sx[0] = __shfl_xor(wdpd[0], 32, 64);
                sx[1] = __shfl_xor(wdpd[1], 32, 64);
                wdpd += sx;
            }
            float w_ = __builtin_amdgcn_rcpf(1.f + __expf(-(wdpd[0] + bm0)));
            f32x4 w4 = {w_, w_, w_, w_};
            #pragma unroll
            for (int nt = 0; nt < 5; ++nt)
                wmacc[nt] = __builtin_elementwise_fma(w4, acc[nt], wmacc[nt]);
            f32x4 pd4 = {wdpd[1], wdpd[1], wdpd[1], wdpd[1]};
            xacc = __builtin_elementwise_fma(pd4, xjv, xacc);

            bc0 = nbc0; bc1 = nbc1; bct = nbct;
        } // s
    } // q

    // ---- finalize: sum across the 16 edge-lanes of each row ----
    #pragma unroll
    for (int nt = 0; nt < 5; ++nt)
        #pragma unroll
        for (int r = 0; r < 4; ++r)
            wmacc[nt][r] = red16(wmacc[nt][r]);
    #pragma unroll
    for (int q = 0; q < 4; ++q) xacc[q] = red16(xacc[q]);

    if (c16 == 0) {
        #pragma unroll
        for (int nt = 0; nt < 5; ++nt)
            #pragma unroll
            for (int r = 0; r < 4; ++r) {
                int ch = nt * 16 + 4 * g + r;
                if (ch < C_) wm_out[node_i * C_ + ch] = wmacc[nt][r];
            }
    }
    if (l == 0)
        *(f32x4*)&xacc_out[node_i * 4] = xacc;
}

// ---------------- Kernel 3: node MLP (chained MFMAs, frag loads) --------
__global__ __launch_bounds__(64) void node_kernel(
    const float* __restrict__ x, const float* __restrict__ h,
    const half8v* __restrict__ frags,
    const float* __restrict__ wm, const float* __restrict__ xacc,
    float* __restrict__ hout, float* __restrict__ xout)
{
    __shared__ _Float16 g_s[16][88];
    const int l = threadIdx.x, c16 = l & 15, g = l >> 4;
    const int m0 = blockIdx.x * 16;

    const float* hrow  = h  + (m0 + c16) * C_;
    const float* wmrow = wm + (m0 + c16) * C_;

    // ---- GEMM1: [h|wm|1] (K=160) @ Wh1(+bh1 row 144) ----
    half8v a[5];
    #pragma unroll
    for (int kt = 0; kt < 5; ++kt) {
        int k = kt * 32 + g * 8;
        half8v v = {};
        if (k < C_) v = cvt8(hrow + k);
        else if (k < 144) v = cvt8(wmrow + (k - C_));
        else if (k == 144) v[0] = (_Float16)1.0f;
        a[kt] = v;
    }
    f32x4 acc1[5] = {};
    #pragma unroll
    for (int kt = 0; kt < 5; ++kt)
        #pragma unroll
        for (int nt = 0; nt < 5; ++nt)
            acc1[nt] = __builtin_amdgcn_mfma_f32_16x16x32_f16(
                a[kt], frags[FRAG_WH1 + (kt * 5 + nt) * 64 + l], acc1[nt], 0, 0, 0);

    // relu -> wave-local LDS transpose (D layout -> A-fragment layout)
    #pragma unroll
    for (int nt = 0; nt < 5; ++nt) {
        int n = nt * 16 + c16;
        #pragma unroll
        for (int r = 0; r < 4; ++r)
            g_s[4 * g + r][n] = (_Float16)fmaxf(acc1[nt][r], 0.f);
    }
    __syncthreads();
    half8v b0 = *(const half8v*)&g_s[c16][g * 8];
    half8v b1 = *(const half8v*)&g_s[c16][32 + g * 8];
    half8v b2 = {};
    if (g == 0) b2 = *(const half8v*)&g_s[c16][64];
    else if (g == 1) b2[0] = (_Float16)1.0f;   // bh2 bias row k=72

    // ---- GEMM2: g (K=96) @ Wh2(+bh2 row 72) ----
    f32x4 acc2[5] = {};
    #pragma unroll
    for (int kt = 0; kt < 3; ++kt) {
        half8v aa = (kt == 0) ? b0 : (kt == 1 ? b1 : b2);
        #pragma unroll
        for (int nt = 0; nt < 5; ++nt)
            acc2[nt] = __builtin_amdgcn_mfma_f32_16x16x32_f16(
                aa, frags[FRAG_WH2 + (kt * 5 + nt) * 64 + l], acc2[nt], 0, 0, 0);
    }
    #pragma unroll
    for (int nt = 0; nt < 5; ++nt) {
        int n = nt * 16 + c16;
        if (n < C_) {
            #pragma unroll
            for (int r = 0; r < 4; ++r) {
                int row = m0 + 4 * g + r;
                hout[row * C_ + n] = h[row * C_ + n] + acc2[nt][r];
            }
        }
    }
    {
        int row = m0 + (l >> 2), d = l & 3;
        xout[row * 4 + d] = x[row * 4 + d] + 0.005f * (xacc[row * 4 + d] * (1.0f / 128.f));
    }
}

extern "C" void kernel_launch(void* const* d_in, const int* in_sizes, int n_in,
                              void* d_out, int out_size, void* d_ws, size_t ws_size,
                              hipStream_t stream) {
    const float* x   = (const float*)d_in[0];
    const float* h   = (const float*)d_in[1];
    const float* We1 = (const float*)d_in[2];
    const float* be1 = (const float*)d_in[3];
    const float* We2 = (const float*)d_in[4];
    const float* be2 = (const float*)d_in[5];
    const float* Wm  = (const float*)d_in[6];
    const float* bm  = (const float*)d_in[7];
    const float* Wh1 = (const float*)d_in[8];
    const float* bh1 = (const float*)d_in[9];
    const float* Wh2 = (const float*)d_in[10];
    const float* bh2 = (const float*)d_in[11];
    const float* Wx  = (const float*)d_in[12];

    const int NNODE = B_ * P_;                        // 8192
    _Float16* Ah  = (_Float16*)d_ws;                  // [8192][80] f16
    half8v* Bcf   = (half8v*)(Ah + NNODE * PADC);     // 64*8*2*64 half8v = 1 MB
    half4v* Bcft  = (half4v*)(Bcf + B_ * 8 * 2 * 64); // 64*8*64 half4v = 256 KB
    float* wm     = (float*)(Bcft + B_ * 8 * 64);     // [8192][72] f32
    float* xacc   = wm + NNODE * C_;                  // [8192][4]  f32
    half8v* frags = (half8v*)(xacc + NNODE * 4);      // 85 frags + 5 tail + w12p

    float* hout = (float*)d_out;                      // [8192][72]
    float* xout = hout + NNODE * C_;                  // [8192][4]

    setup_kernel<<<NFRAG + 6, 64, 0, stream>>>(We1, be1, We2, be2, Wh1, bh1, Wh2, bh2, frags);
    pre_kernel<<<NNODE / 16 * 2, 64, 0, stream>>>(h, frags, Ah, Bcf, Bcft);
    edge_kernel<<<B_ * 32, 256, 0, stream>>>(x, Ah, Bcf, Bcft, frags,
                                             Wm, bm, Wx, wm, xacc);
    node_kernel<<<NNODE / 16, 64, 0, stream>>>(x, h, frags, wm, xacc, hout, xout);
}

// Round 15
// 54.453 us; speedup vs baseline: 4.9006x; 1.0511x over previous
//
#include <hip/hip_runtime.h>
#include <hip/hip_bf16.h>
#include <math.h>

#define B_ 64
#define P_ 128
#define C_ 72
#define PADC 80    // f16 global row stride for Ah
#define IT 8       // i-rows per edge block (2 per wave, ii-outer)

typedef __attribute__((ext_vector_type(8))) _Float16 half8v;
typedef __attribute__((ext_vector_type(4))) _Float16 half4v;
typedef __attribute__((ext_vector_type(4))) float f32x4;
typedef __attribute__((ext_vector_type(2))) float f32x2;

// precomputed weight-fragment table (units: half8v, 64 per fragment)
#define FRAG_WE2  0          // We2 kt=0,1 (K32), 15 frag slots
#define FRAG_WE1A (15 * 64)  // We1 rows 0..71, 15 frags
#define FRAG_WE1B (30 * 64)  // We1 rows 72..143 (+be1 @k=72), 15 frags
#define FRAG_WH1  (45 * 64)  // Wh1 (+bh1 @k=144), 25 frags
#define FRAG_WH2  (70 * 64)  // Wh2 (+bh2 @k=72), 15 frags
#define NFRAG 85             // + 5 K16-tail frags + w12p + wmwxp appended

__device__ __forceinline__ float psi_f(float v) {
    float a = fabsf(v);
    return copysignf(__logf(1.0f + a), v);
}
template <int CTRL>
__device__ __forceinline__ float dpp_add(float v) {
    int s = __builtin_amdgcn_update_dpp(0, __builtin_bit_cast(int, v), CTRL, 0xF, 0xF, true);
    return v + __builtin_bit_cast(float, s);
}
// full sum across each 16-lane group (fixed tree -> deterministic)
__device__ __forceinline__ float red16(float v) {
    v = dpp_add<0xB1>(v);    // quad_perm(1,0,3,2)
    v = dpp_add<0x4E>(v);    // quad_perm(2,3,0,1)
    v = dpp_add<0x141>(v);   // row_half_mirror
    v = dpp_add<0x140>(v);   // row_mirror
    return v;
}
__device__ __forceinline__ half8v cvt8(const float* p) {
    f32x4 a = *(const f32x4*)p;
    f32x4 b = *(const f32x4*)(p + 4);
    half8v r = {(_Float16)a[0], (_Float16)a[1], (_Float16)a[2], (_Float16)a[3],
                (_Float16)b[0], (_Float16)b[1], (_Float16)b[2], (_Float16)b[3]};
    return r;
}

// ---------------- Kernel 0: build all weight fragments ------------------
__global__ __launch_bounds__(64) void setup_kernel(
    const float* __restrict__ We1, const float* __restrict__ be1,
    const float* __restrict__ We2, const float* __restrict__ be2,
    const float* __restrict__ Wh1, const float* __restrict__ bh1,
    const float* __restrict__ Wh2, const float* __restrict__ bh2,
    const float* __restrict__ Wm, const float* __restrict__ Wx,
    half8v* __restrict__ frags)
{
    const int bid = blockIdx.x;
    const int l = threadIdx.x;
    const int c16 = l & 15, g = l >> 4;

    if (bid == NFRAG + 5) {
        // padded w144/w145 table: w12p[2][80], zeros beyond col 71
        _Float16* w12p = (_Float16*)((half4v*)(frags + NFRAG * 64) + 5 * 64);
        for (int i = l; i < 160; i += 64) {
            int s = i / 80, c = i - s * 80;
            w12p[i] = (c < C_) ? (_Float16)We1[(144 + s) * C_ + c] : (_Float16)0.f;
        }
        // packed (Wm, Wx) pair table, padded to 80
        f32x2* wmwxp = (f32x2*)(w12p + 160);
        for (int idx = l; idx < 80; idx += 64) {
            f32x2 v;
            v[0] = (idx < C_) ? Wm[idx] : 0.f;
            v[1] = (idx < C_) ? Wx[idx] : 0.f;
            wmwxp[idx] = v;
        }
        return;
    }
    if (bid >= NFRAG) {
        // K16 tail frags for edge We2: k = 64 + 4g + jj, bias(be2) at k=72
        half4v* tail = (half4v*)(frags + NFRAG * 64);
        const int nt = bid - NFRAG;
        const int n = nt * 16 + c16;
        half4v f = {};
        if (n < C_) {
            #pragma unroll
            for (int jj = 0; jj < 4; ++jj) {
                int k = 64 + 4 * g + jj;
                float w = 0.f;
                if (k < C_) w = We2[k * C_ + n];
                else if (k == C_) w = be2[n];
                f[jj] = (_Float16)w;
            }
        }
        tail[nt * 64 + l] = f;
        return;
    }

    const float* W;
    const float* bias;
    int kmax, rel;
    if (bid < 15)      { W = We2;            bias = be2;     kmax = 72;  rel = bid; }
    else if (bid < 30) { W = We1;            bias = nullptr; kmax = 72;  rel = bid - 15; }
    else if (bid < 45) { W = We1 + 72 * C_;  bias = be1;     kmax = 72;  rel = bid - 30; }
    else if (bid < 70) { W = Wh1;            bias = bh1;     kmax = 144; rel = bid - 45; }
    else               { W = Wh2;            bias = bh2;     kmax = 72;  rel = bid - 70; }
    const int kt = rel / 5, nt = rel - 5 * kt;
    const int n = nt * 16 + c16;

    half8v f = {};
    if (n < C_) {
        #pragma unroll
        for (int jj = 0; jj < 8; ++jj) {
            int k = kt * 32 + g * 8 + jj;
            float w = 0.f;
            if (k < kmax) w = W[k * C_ + n];
            else if (k == kmax && bias) w = bias[n];
            f[jj] = (_Float16)w;
        }
    }
    frags[bid * 64 + l] = f;
}

// ---------------- Kernel 1: pre (MFMA) ----------------------------------
// sel=0: A rows (row layout, bias 1.0 baked at col 72).  sel=1: Bc frags.
__global__ __launch_bounds__(64) void pre_kernel(
    const float* __restrict__ h, const half8v* __restrict__ frags,
    _Float16* __restrict__ Ah, half8v* __restrict__ Bcf,
    half4v* __restrict__ Bcft)
{
    __shared__ _Float16 T[16][88];
    const int l = threadIdx.x, c16 = l & 15, g = l >> 4;
    const int sel = blockIdx.x & 1;
    const int m0 = (blockIdx.x >> 1) * 16;

    const float* hrow = h + (m0 + c16) * C_;
    half8v a0 = cvt8(hrow + g * 8);
    half8v a1 = cvt8(hrow + 32 + g * 8);
    half8v a2 = {};
    if (g == 0) a2 = cvt8(hrow + 64);
    else if (g == 1) a2[0] = (_Float16)1.0f;   // bias row k=72

    const half8v* F = frags + (sel ? FRAG_WE1B : FRAG_WE1A);
    f32x4 acc[5] = {};
    #pragma unroll
    for (int kt = 0; kt < 3; ++kt) {
        half8v a = (kt == 0) ? a0 : (kt == 1 ? a1 : a2);
        #pragma unroll
        for (int nt = 0; nt < 5; ++nt)
            acc[nt] = __builtin_amdgcn_mfma_f32_16x16x32_f16(a, F[(kt * 5 + nt) * 64 + l], acc[nt], 0, 0, 0);
    }

    if (sel == 0) {
        #pragma unroll
        for (int nt = 0; nt < 5; ++nt) {
            int n = nt * 16 + c16;
            if (n < C_) {
                #pragma unroll
                for (int r = 0; r < 4; ++r)
                    Ah[(m0 + 4 * g + r) * PADC + n] = (_Float16)acc[nt][r];
            }
        }
        if (l < 16) {   // bake be2-bias marker: col 72 = 1.0, 73..79 = 0
            half4v one = {(_Float16)1.0f, (_Float16)0.f, (_Float16)0.f, (_Float16)0.f};
            half4v z = {};
            *(half4v*)&Ah[(m0 + l) * PADC + 72] = one;
            *(half4v*)&Ah[(m0 + l) * PADC + 76] = z;
        }
    } else {
        // D layout -> LDS -> B-fragment layout
        #pragma unroll
        for (int nt = 0; nt < 5; ++nt) {
            int n = nt * 16 + c16;
            if (n < C_) {
                #pragma unroll
                for (int r = 0; r < 4; ++r)
                    T[4 * g + r][n] = (_Float16)acc[nt][r];
            }
        }
        {   // zero pad cols 72..87
            int zr = l >> 2, zc = 72 + (l & 3) * 4;
            half4v z = {};
            *(half4v*)&T[zr][zc] = z;
        }
        __syncthreads();
        const int bb = m0 >> 7, jt = (m0 >> 4) & 7;
        half8v f0 = *(const half8v*)&T[c16][g * 8];
        half8v f1 = *(const half8v*)&T[c16][32 + g * 8];
        half4v ft = *(const half4v*)&T[c16][64 + g * 4];
        Bcf[((bb * 8 + jt) * 2 + 0) * 64 + l] = f0;
        Bcf[((bb * 8 + jt) * 2 + 1) * 64 + l] = f1;
        Bcft[(bb * 8 + jt) * 64 + l] = ft;
    }
}

// ---------------- Kernel 2: edge MLP — quad-dedup, ii-amortized ---------
__global__ __launch_bounds__(256, 2) void edge_kernel(
    const float* __restrict__ x, const _Float16* __restrict__ Ah,
    const half8v* __restrict__ Bcf, const half4v* __restrict__ Bcft,
    const half8v* __restrict__ frags,
    const float* __restrict__ bm,
    float* __restrict__ wm_out, float* __restrict__ xacc_out)
{
    const int b  = blockIdx.x >> 4;
    const int it = blockIdx.x & 15;
    const int t  = threadIdx.x;
    const int wv = t >> 6;
    const int l  = t & 63;
    const int c16 = l & 15;
    const int g   = l >> 4;

    // ---- We2 fragments: 2x K32 + 1x K16 tail ----
    half8v Wf[2][5];
    #pragma unroll
    for (int kt = 0; kt < 2; ++kt)
        #pragma unroll
        for (int nt = 0; nt < 5; ++nt)
            Wf[kt][nt] = frags[FRAG_WE2 + (kt * 5 + nt) * 64 + l];
    half4v Wf2[5];
    const half4v* tail = (const half4v*)(frags + NFRAG * 64);
    #pragma unroll
    for (int nt = 0; nt < 5; ++nt)
        Wf2[nt] = tail[nt * 64 + l];

    // padded w144/w145 table
    const _Float16* w12p = (const _Float16*)(tail + 5 * 64);
    half8v w1a = *(const half8v*)&w12p[g * 8];
    half8v w1b = *(const half8v*)&w12p[32 + g * 8];
    half4v w1t = *(const half4v*)&w12p[64 + g * 4];
    half8v w2a = *(const half8v*)&w12p[80 + g * 8];
    half8v w2b = *(const half8v*)&w12p[80 + 32 + g * 8];
    half4v w2t = *(const half4v*)&w12p[80 + 64 + g * 4];

    // packed (Wm,Wx) pairs: 10 vector loads instead of 40 scalar
    const f32x2* wmwxp = (const f32x2*)(w12p + 160);
    f32x2 WmWx[5][4];
    #pragma unroll
    for (int nt = 0; nt < 5; ++nt) {
        f32x4 p0 = *(const f32x4*)&wmwxp[nt * 16 + 4 * g];
        f32x4 p1 = *(const f32x4*)&wmwxp[nt * 16 + 4 * g + 2];
        WmWx[nt][0][0] = p0[0]; WmWx[nt][0][1] = p0[1];
        WmWx[nt][1][0] = p0[2]; WmWx[nt][1][1] = p0[3];
        WmWx[nt][2][0] = p1[0]; WmWx[nt][2][1] = p1[1];
        WmWx[nt][3][0] = p1[2]; WmWx[nt][3][1] = p1[3];
    }
    const float bm0 = bm[0];
    const f32x4 zero4 = {0.f, 0.f, 0.f, 0.f};

    const half8v* Bb = Bcf + (size_t)(b * 8) * 2 * 64;
    const half4v* Bt = Bcft + (size_t)(b * 8) * 64;
    const float*  xb = x + b * P_ * 4;
    const int c16_4 = c16 << 2;

    #pragma unroll 1
    for (int ii = 0; ii < 2; ++ii) {
        const int i = it * IT + wv * 2 + ii;
        const int node_i = b * P_ + i;
        const f32x4 xi = *(const f32x4*)&x[node_i * 4];
        const _Float16* Arow = Ah + node_i * PADC;
        half8v a0 = *(const half8v*)&Arow[g * 8];
        half8v a1 = *(const half8v*)&Arow[32 + g * 8];
        half4v at = *(const half4v*)&Arow[64 + g * 4];   // g=2 carries baked bias

        // Bc prefetch, 1-deep
        half8v bc0 = Bb[l];
        half8v bc1 = Bb[64 + l];
        half4v bct = Bt[l];

        f32x4 wmacc[5] = {};
        f32x4 xacc = {0.f, 0.f, 0.f, 0.f};

        #pragma unroll 1
        for (int q = 0; q < 2; ++q) {
            // ---- 64-edge geometry + psi, computed ONCE per 4 tiles ----
            f32x4 xjq = *(const f32x4*)&xb[(q * 64 + l) * 4];
            float d0 = xi[0] - xjq[0], d1 = xi[1] - xjq[1];
            float d2 = xi[2] - xjq[2], d3 = xi[3] - xjq[3];
            float nn = d0 * d0 - d1 * d1 - d2 * d2 - d3 * d3;
            float pp = xi[0] * xjq[0] - xi[1] * xjq[1] - xi[2] * xjq[2] - xi[3] * xjq[3];
            unsigned geo =
                (unsigned)__builtin_bit_cast(unsigned short, (_Float16)psi_f(nn)) |
                ((unsigned)__builtin_bit_cast(unsigned short, (_Float16)psi_f(pp)) << 16);
            int geo0 = __builtin_amdgcn_ds_bpermute(c16_4,       (int)geo);
            int geo1 = __builtin_amdgcn_ds_bpermute(c16_4 + 64,  (int)geo);
            int geo2 = __builtin_amdgcn_ds_bpermute(c16_4 + 128, (int)geo);
            int geo3 = __builtin_amdgcn_ds_bpermute(c16_4 + 192, (int)geo);

            #pragma unroll
            for (int s = 0; s < 4; ++s) {
                const int jt = q * 4 + s;
                const int njt = (jt + 1) & 7;
                half8v nbc0 = Bb[(njt * 2) * 64 + l];
                half8v nbc1 = Bb[(njt * 2 + 1) * 64 + l];
                half4v nbct = Bt[njt * 64 + l];
                f32x4 xjv = *(const f32x4*)&xb[(jt * 16 + c16) * 4];

                int geos = (s == 0) ? geo0 : (s == 1) ? geo1 : (s == 2) ? geo2 : geo3;
                _Float16 nh = __builtin_bit_cast(_Float16, (unsigned short)((unsigned)geos & 0xFFFFu));
                _Float16 ph = __builtin_bit_cast(_Float16, (unsigned short)((unsigned)geos >> 16));
                half8v n8 = {nh, nh, nh, nh, nh, nh, nh, nh};
                half8v p8 = {ph, ph, ph, ph, ph, ph, ph, ph};
                half4v n4 = {nh, nh, nh, nh};
                half4v p4 = {ph, ph, ph, ph};
                half8v zero8 = {};
                half4v zero4h = {};

                // ---- phase A: m1^T fragments (branch-free tail) ----
                half8v v0 = a0 + bc0;
                v0 = __builtin_elementwise_fma(w1a, n8, v0);
                v0 = __builtin_elementwise_fma(w2a, p8, v0);
                half8v af0 = __builtin_elementwise_max(v0, zero8);
                half8v v1 = a1 + bc1;
                v1 = __builtin_elementwise_fma(w1b, n8, v1);
                v1 = __builtin_elementwise_fma(w2b, p8, v1);
                half8v af1 = __builtin_elementwise_max(v1, zero8);
                half4v vt = at + bct;
                vt = __builtin_elementwise_fma(w1t, n4, vt);
                vt = __builtin_elementwise_fma(w2t, p4, vt);
                half4v af2 = __builtin_elementwise_max(vt, zero4h);

                // ---- phase B: D[ch][edge] = We2^T @ m1^T ----
                f32x4 acc[5] = {};
                #pragma unroll
                for (int nt = 0; nt < 5; ++nt)
                    acc[nt] = __builtin_amdgcn_mfma_f32_16x16x32_f16(Wf[0][nt], af0, acc[nt], 0, 0, 0);
                #pragma unroll
                for (int nt = 0; nt < 5; ++nt)
                    acc[nt] = __builtin_amdgcn_mfma_f32_16x16x32_f16(Wf[1][nt], af1, acc[nt], 0, 0, 0);
                #pragma unroll
                for (int nt = 0; nt < 5; ++nt)
                    acc[nt] = __builtin_amdgcn_mfma_f32_16x16x16f16(Wf2[nt], af2, acc[nt], 0, 0, 0);

                // ---- phase C: two independent dot chains ----
                f32x2 wdA = {0.f, 0.f}, wdB = {0.f, 0.f};
                #pragma unroll
                for (int nt = 0; nt < 5; ++nt) {
                    f32x4 m2q = __builtin_elementwise_max(acc[nt], zero4);
                    acc[nt] = m2q;
                    f32x2 e0 = {m2q[0], m2q[0]};
                    f32x2 e1 = {m2q[1], m2q[1]};
                    f32x2 e2 = {m2q[2], m2q[2]};
                    f32x2 e3 = {m2q[3], m2q[3]};
                    wdA = __builtin_elementwise_fma(e0, WmWx[nt][0], wdA);
                    wdB = __builtin_elementwise_fma(e1, WmWx[nt][1], wdB);
                    wdA = __builtin_elementwise_fma(e2, WmWx[nt][2], wdA);
                    wdB = __builtin_elementwise_fma(e3, WmWx[nt][3], wdB);
                }
                f32x2 wdpd = wdA + wdB;
                {
                    f32x2 sx;
                    sx[0] = __shfl_xor(wdpd[0], 16, 64);
                    sx[1] = __shfl_xor(wdpd[1], 16, 64);
                    wdpd += sx;
                    sx[0] = __shfl_xor(wdpd[0], 32, 64);
                    sx[1] = __shfl_xor(wdpd[1], 32, 64);
                    wdpd += sx;
                }
                float w_ = __builtin_amdgcn_rcpf(1.f + __expf(-(wdpd[0] + bm0)));
                f32x4 w4 = {w_, w_, w_, w_};
                #pragma unroll
                for (int nt = 0; nt < 5; ++nt)
                    wmacc[nt] = __builtin_elementwise_fma(w4, acc[nt], wmacc[nt]);
                f32x4 pd4 = {wdpd[1], wdpd[1], wdpd[1], wdpd[1]};
                xacc = __builtin_elementwise_fma(pd4, xjv, xacc);

                bc0 = nbc0; bc1 = nbc1; bct = nbct;
            } // s
        } // q

        // ---- finalize: sum across the 16 edge-lanes of each row ----
        #pragma unroll
        for (int nt = 0; nt < 5; ++nt)
            #pragma unroll
            for (int r = 0; r < 4; ++r)
                wmacc[nt][r] = red16(wmacc[nt][r]);
        #pragma unroll
        for (int q = 0; q < 4; ++q) xacc[q] = red16(xacc[q]);

        if (c16 == 0) {
            #pragma unroll
            for (int nt = 0; nt < 5; ++nt)
                #pragma unroll
                for (int r = 0; r < 4; ++r) {
                    int ch = nt * 16 + 4 * g + r;
                    if (ch < C_) wm_out[node_i * C_ + ch] = wmacc[nt][r];
                }
        }
        if (l == 0)
            *(f32x4*)&xacc_out[node_i * 4] = xacc;
    } // ii
}

// ---------------- Kernel 3: node MLP (chained MFMAs, frag loads) --------
__global__ __launch_bounds__(64) void node_kernel(
    const float* __restrict__ x, const float* __restrict__ h,
    const half8v* __restrict__ frags,
    const float* __restrict__ wm, const float* __restrict__ xacc,
    float* __restrict__ hout, float* __restrict__ xout)
{
    __shared__ _Float16 g_s[16][88];
    const int l = threadIdx.x, c16 = l & 15, g = l >> 4;
    const int m0 = blockIdx.x * 16;

    const float* hrow  = h  + (m0 + c16) * C_;
    const float* wmrow = wm + (m0 + c16) * C_;

    // ---- GEMM1: [h|wm|1] (K=160) @ Wh1(+bh1 row 144) ----
    half8v a[5];
    #pragma unroll
    for (int kt = 0; kt < 5; ++kt) {
        int k = kt * 32 + g * 8;
        half8v v = {};
        if (k < C_) v = cvt8(hrow + k);
        else if (k < 144) v = cvt8(wmrow + (k - C_));
        else if (k == 144) v[0] = (_Float16)1.0f;
        a[kt] = v;
    }
    f32x4 acc1[5] = {};
    #pragma unroll
    for (int kt = 0; kt < 5; ++kt)
        #pragma unroll
        for (int nt = 0; nt < 5; ++nt)
            acc1[nt] = __builtin_amdgcn_mfma_f32_16x16x32_f16(
                a[kt], frags[FRAG_WH1 + (kt * 5 + nt) * 64 + l], acc1[nt], 0, 0, 0);

    // relu -> wave-local LDS transpose (D layout -> A-fragment layout)
    #pragma unroll
    for (int nt = 0; nt < 5; ++nt) {
        int n = nt * 16 + c16;
        #pragma unroll
        for (int r = 0; r < 4; ++r)
            g_s[4 * g + r][n] = (_Float16)fmaxf(acc1[nt][r], 0.f);
    }
    __syncthreads();
    half8v b0 = *(const half8v*)&g_s[c16][g * 8];
    half8v b1 = *(const half8v*)&g_s[c16][32 + g * 8];
    half8v b2 = {};
    if (g == 0) b2 = *(const half8v*)&g_s[c16][64];
    else if (g == 1) b2[0] = (_Float16)1.0f;   // bh2 bias row k=72

    // ---- GEMM2: g (K=96) @ Wh2(+bh2 row 72) ----
    f32x4 acc2[5] = {};
    #pragma unroll
    for (int kt = 0; kt < 3; ++kt) {
        half8v aa = (kt == 0) ? b0 : (kt == 1 ? b1 : b2);
        #pragma unroll
        for (int nt = 0; nt < 5; ++nt)
            acc2[nt] = __builtin_amdgcn_mfma_f32_16x16x32_f16(
                aa, frags[FRAG_WH2 + (kt * 5 + nt) * 64 + l], acc2[nt], 0, 0, 0);
    }
    #pragma unroll
    for (int nt = 0; nt < 5; ++nt) {
        int n = nt * 16 + c16;
        if (n < C_) {
            #pragma unroll
            for (int r = 0; r < 4; ++r) {
                int row = m0 + 4 * g + r;
                hout[row * C_ + n] = h[row * C_ + n] + acc2[nt][r];
            }
        }
    }
    {
        int row = m0 + (l >> 2), d = l & 3;
        xout[row * 4 + d] = x[row * 4 + d] + 0.005f * (xacc[row * 4 + d] * (1.0f / 128.f));
    }
}

extern "C" void kernel_launch(void* const* d_in, const int* in_sizes, int n_in,
                              void* d_out, int out_size, void* d_ws, size_t ws_size,
                              hipStream_t stream) {
    const float* x   = (const float*)d_in[0];
    const float* h   = (const float*)d_in[1];
    const float* We1 = (const float*)d_in[2];
    const float* be1 = (const float*)d_in[3];
    const float* We2 = (const float*)d_in[4];
    const float* be2 = (const float*)d_in[5];
    const float* Wm  = (const float*)d_in[6];
    const float* bm  = (const float*)d_in[7];
    const float* Wh1 = (const float*)d_in[8];
    const float* bh1 = (const float*)d_in[9];
    const float* Wh2 = (const float*)d_in[10];
    const float* bh2 = (const float*)d_in[11];
    const float* Wx  = (const float*)d_in[12];

    const int NNODE = B_ * P_;                        // 8192
    _Float16* Ah  = (_Float16*)d_ws;                  // [8192][80] f16
    half8v* Bcf   = (half8v*)(Ah + NNODE * PADC);     // 64*8*2*64 half8v = 1 MB
    half4v* Bcft  = (half4v*)(Bcf + B_ * 8 * 2 * 64); // 64*8*64 half4v = 256 KB
    float* wm     = (float*)(Bcft + B_ * 8 * 64);     // [8192][72] f32
    float* xacc   = wm + NNODE * C_;                  // [8192][4]  f32
    half8v* frags = (half8v*)(xacc + NNODE * 4);      // 85 frags + tail + w12p + wmwxp

    float* hout = (float*)d_out;                      // [8192][72]
    float* xout = hout + NNODE * C_;                  // [8192][4]

    setup_kernel<<<NFRAG + 6, 64, 0, stream>>>(We1, be1, We2, be2, Wh1, bh1, Wh2, bh2,
                                               Wm, Wx, frags);
    pre_kernel<<<NNODE / 16 * 2, 64, 0, stream>>>(h, frags, Ah, Bcf, Bcft);
    edge_kernel<<<B_ * 16, 256, 0, stream>>>(x, Ah, Bcf, Bcft, frags, bm, wm, xacc);
    node_kernel<<<NNODE / 16, 64, 0, stream>>>(x, h, frags, wm, xacc, hout, xout);
}

// Round 16
// 52.015 us; speedup vs baseline: 5.1303x; 1.0469x over previous
//
#include <hip/hip_runtime.h>
#include <hip/hip_bf16.h>
#include <math.h>

#define B_ 64
#define P_ 128
#define C_ 72
#define PADC 80    // f16 global row stride for Ah
#define IT 8       // i-rows per edge block (2 per wave, ii-outer)

typedef __attribute__((ext_vector_type(8))) _Float16 half8v;
typedef __attribute__((ext_vector_type(4))) _Float16 half4v;
typedef __attribute__((ext_vector_type(4))) float f32x4;
typedef __attribute__((ext_vector_type(2))) float f32x2;

// precomputed weight-fragment table (units: half8v, 64 per fragment)
#define FRAG_WE2  0          // We2 kt=0,1 (K32), 15 frag slots
#define FRAG_WE1A (15 * 64)  // We1 rows 0..71, 15 frags
#define FRAG_WE1B (30 * 64)  // We1 rows 72..143 (+be1 @k=72), 15 frags
#define FRAG_WH1  (45 * 64)  // Wh1 (+bh1 @k=144), 25 frags
#define FRAG_WH2  (70 * 64)  // Wh2 (+bh2 @k=72), 15 frags
#define NFRAG 85             // + 5 K16-tail frags + w12p + wmwxp appended

__device__ __forceinline__ float psi_f(float v) {
    float a = fabsf(v);
    return copysignf(__logf(1.0f + a), v);
}
template <int CTRL>
__device__ __forceinline__ float dpp_add(float v) {
    int s = __builtin_amdgcn_update_dpp(0, __builtin_bit_cast(int, v), CTRL, 0xF, 0xF, true);
    return v + __builtin_bit_cast(float, s);
}
// full sum across each 16-lane group (fixed tree -> deterministic)
__device__ __forceinline__ float red16(float v) {
    v = dpp_add<0xB1>(v);    // quad_perm(1,0,3,2)
    v = dpp_add<0x4E>(v);    // quad_perm(2,3,0,1)
    v = dpp_add<0x141>(v);   // row_half_mirror
    v = dpp_add<0x140>(v);   // row_mirror
    return v;
}
__device__ __forceinline__ half8v cvt8(const float* p) {
    f32x4 a = *(const f32x4*)p;
    f32x4 b = *(const f32x4*)(p + 4);
    half8v r = {(_Float16)a[0], (_Float16)a[1], (_Float16)a[2], (_Float16)a[3],
                (_Float16)b[0], (_Float16)b[1], (_Float16)b[2], (_Float16)b[3]};
    return r;
}

// ---------------- Kernel 0: build all weight fragments ------------------
__global__ __launch_bounds__(64) void setup_kernel(
    const float* __restrict__ We1, const float* __restrict__ be1,
    const float* __restrict__ We2, const float* __restrict__ be2,
    const float* __restrict__ Wh1, const float* __restrict__ bh1,
    const float* __restrict__ Wh2, const float* __restrict__ bh2,
    const float* __restrict__ Wm, const float* __restrict__ Wx,
    half8v* __restrict__ frags)
{
    const int bid = blockIdx.x;
    const int l = threadIdx.x;
    const int c16 = l & 15, g = l >> 4;

    if (bid == NFRAG + 5) {
        // padded w144/w145 table: w12p[2][80], zeros beyond col 71
        _Float16* w12p = (_Float16*)((half4v*)(frags + NFRAG * 64) + 5 * 64);
        for (int i = l; i < 160; i += 64) {
            int s = i / 80, c = i - s * 80;
            w12p[i] = (c < C_) ? (_Float16)We1[(144 + s) * C_ + c] : (_Float16)0.f;
        }
        // packed (Wm, Wx) pair table, padded to 80
        f32x2* wmwxp = (f32x2*)(w12p + 160);
        for (int idx = l; idx < 80; idx += 64) {
            f32x2 v;
            v[0] = (idx < C_) ? Wm[idx] : 0.f;
            v[1] = (idx < C_) ? Wx[idx] : 0.f;
            wmwxp[idx] = v;
        }
        return;
    }
    if (bid >= NFRAG) {
        // K16 tail frags for edge We2: k = 64 + 4g + jj, bias(be2) at k=72
        half4v* tail = (half4v*)(frags + NFRAG * 64);
        const int nt = bid - NFRAG;
        const int n = nt * 16 + c16;
        half4v f = {};
        if (n < C_) {
            #pragma unroll
            for (int jj = 0; jj < 4; ++jj) {
                int k = 64 + 4 * g + jj;
                float w = 0.f;
                if (k < C_) w = We2[k * C_ + n];
                else if (k == C_) w = be2[n];
                f[jj] = (_Float16)w;
            }
        }
        tail[nt * 64 + l] = f;
        return;
    }

    const float* W;
    const float* bias;
    int kmax, rel;
    if (bid < 15)      { W = We2;            bias = be2;     kmax = 72;  rel = bid; }
    else if (bid < 30) { W = We1;            bias = nullptr; kmax = 72;  rel = bid - 15; }
    else if (bid < 45) { W = We1 + 72 * C_;  bias = be1;     kmax = 72;  rel = bid - 30; }
    else if (bid < 70) { W = Wh1;            bias = bh1;     kmax = 144; rel = bid - 45; }
    else               { W = Wh2;            bias = bh2;     kmax = 72;  rel = bid - 70; }
    const int kt = rel / 5, nt = rel - 5 * kt;
    const int n = nt * 16 + c16;

    half8v f = {};
    if (n < C_) {
        #pragma unroll
        for (int jj = 0; jj < 8; ++jj) {
            int k = kt * 32 + g * 8 + jj;
            float w = 0.f;
            if (k < kmax) w = W[k * C_ + n];
            else if (k == kmax && bias) w = bias[n];
            f[jj] = (_Float16)w;
        }
    }
    frags[bid * 64 + l] = f;
}

// ---------------- Kernel 1: pre (MFMA) ----------------------------------
// sel=0: A rows (row layout, bias 1.0 baked at col 72).  sel=1: Bc frags.
__global__ __launch_bounds__(64) void pre_kernel(
    const float* __restrict__ h, const half8v* __restrict__ frags,
    _Float16* __restrict__ Ah, half8v* __restrict__ Bcf,
    half4v* __restrict__ Bcft)
{
    __shared__ _Float16 T[16][88];
    const int l = threadIdx.x, c16 = l & 15, g = l >> 4;
    const int sel = blockIdx.x & 1;
    const int m0 = (blockIdx.x >> 1) * 16;

    const float* hrow = h + (m0 + c16) * C_;
    half8v a0 = cvt8(hrow + g * 8);
    half8v a1 = cvt8(hrow + 32 + g * 8);
    half8v a2 = {};
    if (g == 0) a2 = cvt8(hrow + 64);
    else if (g == 1) a2[0] = (_Float16)1.0f;   // bias row k=72

    const half8v* F = frags + (sel ? FRAG_WE1B : FRAG_WE1A);
    f32x4 acc[5] = {};
    #pragma unroll
    for (int kt = 0; kt < 3; ++kt) {
        half8v a = (kt == 0) ? a0 : (kt == 1 ? a1 : a2);
        #pragma unroll
        for (int nt = 0; nt < 5; ++nt)
            acc[nt] = __builtin_amdgcn_mfma_f32_16x16x32_f16(a, F[(kt * 5 + nt) * 64 + l], acc[nt], 0, 0, 0);
    }

    if (sel == 0) {
        #pragma unroll
        for (int nt = 0; nt < 5; ++nt) {
            int n = nt * 16 + c16;
            if (n < C_) {
                #pragma unroll
                for (int r = 0; r < 4; ++r)
                    Ah[(m0 + 4 * g + r) * PADC + n] = (_Float16)acc[nt][r];
            }
        }
        if (l < 16) {   // bake be2-bias marker: col 72 = 1.0, 73..79 = 0
            half4v one = {(_Float16)1.0f, (_Float16)0.f, (_Float16)0.f, (_Float16)0.f};
            half4v z = {};
            *(half4v*)&Ah[(m0 + l) * PADC + 72] = one;
            *(half4v*)&Ah[(m0 + l) * PADC + 76] = z;
        }
    } else {
        // D layout -> LDS -> B-fragment layout
        #pragma unroll
        for (int nt = 0; nt < 5; ++nt) {
            int n = nt * 16 + c16;
            if (n < C_) {
                #pragma unroll
                for (int r = 0; r < 4; ++r)
                    T[4 * g + r][n] = (_Float16)acc[nt][r];
            }
        }
        {   // zero pad cols 72..87
            int zr = l >> 2, zc = 72 + (l & 3) * 4;
            half4v z = {};
            *(half4v*)&T[zr][zc] = z;
        }
        __syncthreads();
        const int bb = m0 >> 7, jt = (m0 >> 4) & 7;
        half8v f0 = *(const half8v*)&T[c16][g * 8];
        half8v f1 = *(const half8v*)&T[c16][32 + g * 8];
        half4v ft = *(const half4v*)&T[c16][64 + g * 4];
        Bcf[((bb * 8 + jt) * 2 + 0) * 64 + l] = f0;
        Bcf[((bb * 8 + jt) * 2 + 1) * 64 + l] = f1;
        Bcft[(bb * 8 + jt) * 64 + l] = ft;
    }
}

// ---------------- Kernel 2: edge MLP + fused node MLP -------------------
__global__ __launch_bounds__(256, 2) void edge_kernel(
    const float* __restrict__ x, const float* __restrict__ h,
    const _Float16* __restrict__ Ah,
    const half8v* __restrict__ Bcf, const half4v* __restrict__ Bcft,
    const half8v* __restrict__ frags,
    const float* __restrict__ bm,
    float* __restrict__ hout, float* __restrict__ xout)
{
    __shared__ float wm_s[IT][80];          // this block's wm rows (f32)
    __shared__ _Float16 g_s[16][88];        // node GEMM1 transpose buffer

    const int b  = blockIdx.x >> 4;
    const int it = blockIdx.x & 15;
    const int t  = threadIdx.x;
    const int wv = t >> 6;
    const int l  = t & 63;
    const int c16 = l & 15;
    const int g   = l >> 4;

    // ---- We2 fragments: 2x K32 + 1x K16 tail ----
    half8v Wf[2][5];
    #pragma unroll
    for (int kt = 0; kt < 2; ++kt)
        #pragma unroll
        for (int nt = 0; nt < 5; ++nt)
            Wf[kt][nt] = frags[FRAG_WE2 + (kt * 5 + nt) * 64 + l];
    half4v Wf2[5];
    const half4v* tail = (const half4v*)(frags + NFRAG * 64);
    #pragma unroll
    for (int nt = 0; nt < 5; ++nt)
        Wf2[nt] = tail[nt * 64 + l];

    // padded w144/w145 table
    const _Float16* w12p = (const _Float16*)(tail + 5 * 64);
    half8v w1a = *(const half8v*)&w12p[g * 8];
    half8v w1b = *(const half8v*)&w12p[32 + g * 8];
    half4v w1t = *(const half4v*)&w12p[64 + g * 4];
    half8v w2a = *(const half8v*)&w12p[80 + g * 8];
    half8v w2b = *(const half8v*)&w12p[80 + 32 + g * 8];
    half4v w2t = *(const half4v*)&w12p[80 + 64 + g * 4];

    // packed (Wm,Wx) pairs: 10 vector loads instead of 40 scalar
    const f32x2* wmwxp = (const f32x2*)(w12p + 160);
    f32x2 WmWx[5][4];
    #pragma unroll
    for (int nt = 0; nt < 5; ++nt) {
        f32x4 p0 = *(const f32x4*)&wmwxp[nt * 16 + 4 * g];
        f32x4 p1 = *(const f32x4*)&wmwxp[nt * 16 + 4 * g + 2];
        WmWx[nt][0][0] = p0[0]; WmWx[nt][0][1] = p0[1];
        WmWx[nt][1][0] = p0[2]; WmWx[nt][1][1] = p0[3];
        WmWx[nt][2][0] = p1[0]; WmWx[nt][2][1] = p1[1];
        WmWx[nt][3][0] = p1[2]; WmWx[nt][3][1] = p1[3];
    }
    const float bm0 = bm[0];
    const f32x4 zero4 = {0.f, 0.f, 0.f, 0.f};

    const half8v* Bb = Bcf + (size_t)(b * 8) * 2 * 64;
    const half4v* Bt = Bcft + (size_t)(b * 8) * 64;
    const float*  xb = x + b * P_ * 4;
    const int c16_4 = c16 << 2;
    const int m0row = b * P_ + it * IT;

    #pragma unroll 1
    for (int ii = 0; ii < 2; ++ii) {
        const int rowl = wv * 2 + ii;
        const int node_i = m0row + rowl;
        const f32x4 xi = *(const f32x4*)&x[node_i * 4];
        const _Float16* Arow = Ah + node_i * PADC;
        half8v a0 = *(const half8v*)&Arow[g * 8];
        half8v a1 = *(const half8v*)&Arow[32 + g * 8];
        half4v at = *(const half4v*)&Arow[64 + g * 4];   // g=2 carries baked bias

        // Bc prefetch, 1-deep
        half8v bc0 = Bb[l];
        half8v bc1 = Bb[64 + l];
        half4v bct = Bt[l];

        f32x4 wmacc[5] = {};
        f32x4 xacc = {0.f, 0.f, 0.f, 0.f};

        #pragma unroll 1
        for (int q = 0; q < 2; ++q) {
            // ---- 64-edge geometry + psi, computed ONCE per 4 tiles ----
            f32x4 xjq = *(const f32x4*)&xb[(q * 64 + l) * 4];
            float d0 = xi[0] - xjq[0], d1 = xi[1] - xjq[1];
            float d2 = xi[2] - xjq[2], d3 = xi[3] - xjq[3];
            float nn = d0 * d0 - d1 * d1 - d2 * d2 - d3 * d3;
            float pp = xi[0] * xjq[0] - xi[1] * xjq[1] - xi[2] * xjq[2] - xi[3] * xjq[3];
            unsigned geo =
                (unsigned)__builtin_bit_cast(unsigned short, (_Float16)psi_f(nn)) |
                ((unsigned)__builtin_bit_cast(unsigned short, (_Float16)psi_f(pp)) << 16);
            int geo0 = __builtin_amdgcn_ds_bpermute(c16_4,       (int)geo);
            int geo1 = __builtin_amdgcn_ds_bpermute(c16_4 + 64,  (int)geo);
            int geo2 = __builtin_amdgcn_ds_bpermute(c16_4 + 128, (int)geo);
            int geo3 = __builtin_amdgcn_ds_bpermute(c16_4 + 192, (int)geo);

            #pragma unroll
            for (int s = 0; s < 4; ++s) {
                const int jt = q * 4 + s;
                const int njt = (jt + 1) & 7;
                half8v nbc0 = Bb[(njt * 2) * 64 + l];
                half8v nbc1 = Bb[(njt * 2 + 1) * 64 + l];
                half4v nbct = Bt[njt * 64 + l];
                f32x4 xjv = *(const f32x4*)&xb[(jt * 16 + c16) * 4];

                int geos = (s == 0) ? geo0 : (s == 1) ? geo1 : (s == 2) ? geo2 : geo3;
                _Float16 nh = __builtin_bit_cast(_Float16, (unsigned short)((unsigned)geos & 0xFFFFu));
                _Float16 ph = __builtin_bit_cast(_Float16, (unsigned short)((unsigned)geos >> 16));
                half8v n8 = {nh, nh, nh, nh, nh, nh, nh, nh};
                half8v p8 = {ph, ph, ph, ph, ph, ph, ph, ph};
                half4v n4 = {nh, nh, nh, nh};
                half4v p4 = {ph, ph, ph, ph};
                half8v zero8 = {};
                half4v zero4h = {};

                // ---- phase A: m1^T fragments (branch-free tail) ----
                half8v v0 = a0 + bc0;
                v0 = __builtin_elementwise_fma(w1a, n8, v0);
                v0 = __builtin_elementwise_fma(w2a, p8, v0);
                half8v af0 = __builtin_elementwise_max(v0, zero8);
                half8v v1 = a1 + bc1;
                v1 = __builtin_elementwise_fma(w1b, n8, v1);
                v1 = __builtin_elementwise_fma(w2b, p8, v1);
                half8v af1 = __builtin_elementwise_max(v1, zero8);
                half4v vt = at + bct;
                vt = __builtin_elementwise_fma(w1t, n4, vt);
                vt = __builtin_elementwise_fma(w2t, p4, vt);
                half4v af2 = __builtin_elementwise_max(vt, zero4h);

                // ---- phase B: D[ch][edge] = We2^T @ m1^T ----
                f32x4 acc[5] = {};
                #pragma unroll
                for (int nt = 0; nt < 5; ++nt)
                    acc[nt] = __builtin_amdgcn_mfma_f32_16x16x32_f16(Wf[0][nt], af0, acc[nt], 0, 0, 0);
                #pragma unroll
                for (int nt = 0; nt < 5; ++nt)
                    acc[nt] = __builtin_amdgcn_mfma_f32_16x16x32_f16(Wf[1][nt], af1, acc[nt], 0, 0, 0);
                #pragma unroll
                for (int nt = 0; nt < 5; ++nt)
                    acc[nt] = __builtin_amdgcn_mfma_f32_16x16x16f16(Wf2[nt], af2, acc[nt], 0, 0, 0);

                // ---- phase C: two independent dot chains ----
                f32x2 wdA = {0.f, 0.f}, wdB = {0.f, 0.f};
                #pragma unroll
                for (int nt = 0; nt < 5; ++nt) {
                    f32x4 m2q = __builtin_elementwise_max(acc[nt], zero4);
                    acc[nt] = m2q;
                    f32x2 e0 = {m2q[0], m2q[0]};
                    f32x2 e1 = {m2q[1], m2q[1]};
                    f32x2 e2 = {m2q[2], m2q[2]};
                    f32x2 e3 = {m2q[3], m2q[3]};
                    wdA = __builtin_elementwise_fma(e0, WmWx[nt][0], wdA);
                    wdB = __builtin_elementwise_fma(e1, WmWx[nt][1], wdB);
                    wdA = __builtin_elementwise_fma(e2, WmWx[nt][2], wdA);
                    wdB = __builtin_elementwise_fma(e3, WmWx[nt][3], wdB);
                }
                f32x2 wdpd = wdA + wdB;
                {
                    f32x2 sx;
                    sx[0] = __shfl_xor(wdpd[0], 16, 64);
                    sx[1] = __shfl_xor(wdpd[1], 16, 64);
                    wdpd += sx;
                    sx[0] = __shfl_xor(wdpd[0], 32, 64);
                    sx[1] = __shfl_xor(wdpd[1], 32, 64);
                    wdpd += sx;
                }
                float w_ = __builtin_amdgcn_rcpf(1.f + __expf(-(wdpd[0] + bm0)));
                f32x4 w4 = {w_, w_, w_, w_};
                #pragma unroll
                for (int nt = 0; nt < 5; ++nt)
                    wmacc[nt] = __builtin_elementwise_fma(w4, acc[nt], wmacc[nt]);
                f32x4 pd4 = {wdpd[1], wdpd[1], wdpd[1], wdpd[1]};
                xacc = __builtin_elementwise_fma(pd4, xjv, xacc);

                bc0 = nbc0; bc1 = nbc1; bct = nbct;
            } // s
        } // q

        // ---- finalize: sum across the 16 edge-lanes; stash wm in LDS ----
        #pragma unroll
        for (int nt = 0; nt < 5; ++nt)
            #pragma unroll
            for (int r = 0; r < 4; ++r)
                wmacc[nt][r] = red16(wmacc[nt][r]);
        #pragma unroll
        for (int q = 0; q < 4; ++q) xacc[q] = red16(xacc[q]);

        if (c16 == 0) {
            #pragma unroll
            for (int nt = 0; nt < 5; ++nt)
                #pragma unroll
                for (int r = 0; r < 4; ++r) {
                    int ch = nt * 16 + 4 * g + r;
                    if (ch < C_) wm_s[rowl][ch] = wmacc[nt][r];
                }
        }
        if (l == 0) {
            f32x4 xo = xi + 0.005f * (1.0f / 128.f) * xacc;
            *(f32x4*)&xout[node_i * 4] = xo;
        }
    } // ii

    __syncthreads();   // all waves' wm rows visible

    // ---- fused node MLP (wave 0 only; 8 rows duplicated to 16) ----
    if (wv != 0) return;
    {
        const int row = c16 & 7;                    // duplicate 8 rows
        const float* hrow = h + (m0row + row) * C_;

        // GEMM1: [h|wm|1] (K=160) @ Wh1(+bh1 row 144)
        half8v a[5];
        #pragma unroll
        for (int kt = 0; kt < 5; ++kt) {
            int k = kt * 32 + g * 8;
            half8v v = {};
            if (k < C_) v = cvt8(hrow + k);
            else if (k < 144) v = cvt8(&wm_s[row][k - C_]);
            else if (k == 144) v[0] = (_Float16)1.0f;
            a[kt] = v;
        }
        f32x4 acc1[5] = {};
        #pragma unroll
        for (int kt = 0; kt < 5; ++kt)
            #pragma unroll
            for (int nt = 0; nt < 5; ++nt)
                acc1[nt] = __builtin_amdgcn_mfma_f32_16x16x32_f16(
                    a[kt], frags[FRAG_WH1 + (kt * 5 + nt) * 64 + l], acc1[nt], 0, 0, 0);

        // relu -> wave-local LDS transpose (D layout -> A-fragment layout)
        #pragma unroll
        for (int nt = 0; nt < 5; ++nt) {
            int n = nt * 16 + c16;
            #pragma unroll
            for (int r = 0; r < 4; ++r)
                g_s[4 * g + r][n] = (_Float16)fmaxf(acc1[nt][r], 0.f);
        }
        // wave-local RAW: compiler inserts lgkmcnt wait (no barrier needed)
        half8v b0 = *(const half8v*)&g_s[c16][g * 8];
        half8v b1 = *(const half8v*)&g_s[c16][32 + g * 8];
        half8v b2 = {};
        if (g == 0) b2 = *(const half8v*)&g_s[c16][64];
        else if (g == 1) b2[0] = (_Float16)1.0f;   // bh2 bias row k=72

        // GEMM2: g (K=96) @ Wh2(+bh2 row 72)
        f32x4 acc2[5] = {};
        #pragma unroll
        for (int kt = 0; kt < 3; ++kt) {
            half8v aa = (kt == 0) ? b0 : (kt == 1 ? b1 : b2);
            #pragma unroll
            for (int nt = 0; nt < 5; ++nt)
                acc2[nt] = __builtin_amdgcn_mfma_f32_16x16x32_f16(
                    aa, frags[FRAG_WH2 + (kt * 5 + nt) * 64 + l], acc2[nt], 0, 0, 0);
        }
        // store rows 0..7 only (g<2 covers D rows 0..7)
        if (g < 2) {
            #pragma unroll
            for (int nt = 0; nt < 5; ++nt) {
                int n = nt * 16 + c16;
                if (n < C_) {
                    #pragma unroll
                    for (int r = 0; r < 4; ++r) {
                        int rw = m0row + 4 * g + r;
                        hout[rw * C_ + n] = h[rw * C_ + n] + acc2[nt][r];
                    }
                }
            }
        }
    }
}

extern "C" void kernel_launch(void* const* d_in, const int* in_sizes, int n_in,
                              void* d_out, int out_size, void* d_ws, size_t ws_size,
                              hipStream_t stream) {
    const float* x   = (const float*)d_in[0];
    const float* h   = (const float*)d_in[1];
    const float* We1 = (const float*)d_in[2];
    const float* be1 = (const float*)d_in[3];
    const float* We2 = (const float*)d_in[4];
    const float* be2 = (const float*)d_in[5];
    const float* Wm  = (const float*)d_in[6];
    const float* bm  = (const float*)d_in[7];
    const float* Wh1 = (const float*)d_in[8];
    const float* bh1 = (const float*)d_in[9];
    const float* Wh2 = (const float*)d_in[10];
    const float* bh2 = (const float*)d_in[11];
    const float* Wx  = (const float*)d_in[12];

    const int NNODE = B_ * P_;                        // 8192
    _Float16* Ah  = (_Float16*)d_ws;                  // [8192][80] f16
    half8v* Bcf   = (half8v*)(Ah + NNODE * PADC);     // 64*8*2*64 half8v = 1 MB
    half4v* Bcft  = (half4v*)(Bcf + B_ * 8 * 2 * 64); // 64*8*64 half4v = 256 KB
    half8v* frags = (half8v*)(Bcft + B_ * 8 * 64);    // 85 frags + tail + w12p + wmwxp

    float* hout = (float*)d_out;                      // [8192][72]
    float* xout = hout + NNODE * C_;                  // [8192][4]

    setup_kernel<<<NFRAG + 6, 64, 0, stream>>>(We1, be1, We2, be2, Wh1, bh1, Wh2, bh2,
                                               Wm, Wx, frags);
    pre_kernel<<<NNODE / 16 * 2, 64, 0, stream>>>(h, frags, Ah, Bcf, Bcft);
    edge_kernel<<<B_ * 16, 256, 0, stream>>>(x, h, Ah, Bcf, Bcft, frags, bm, hout, xout);
}